// Round 1
// baseline (12523.763 us; speedup 1.0000x reference)
//
#include <hip/hip_runtime.h>
#include <math.h>

#define BQ    4
#define TT    4096
#define DD    512
#define HH    8
#define DHH   64
#define NH    4
#define BSZ   64
#define NBK   64
#define LLAY  4
#define DFFN  2048
#define BHH   32          // B*H
#define NC    256         // chunks per bh (NH*NB)
#define MROWS 16384       // B*T

// ---------------------------------------------------------------------------
// Generic fp32 GEMM: C = op(A @ W^T + bias) [+ resid]
// A: (M,K) row-major, W: (N,K) row-major, C: (M,N)
// BM=BN=128, BK=16, 256 threads, 8x8 per thread.
// ---------------------------------------------------------------------------
__global__ __launch_bounds__(256) void gemm_k(
    const float* __restrict__ A, const float* __restrict__ W,
    const float* __restrict__ bias, const float* __restrict__ resid,
    float* __restrict__ C, int M, int N, int K, int relu)
{
    __shared__ float As[16][128];
    __shared__ float Ws[16][128];
    const int tid = threadIdx.x;
    const int tx = tid & 15, ty = tid >> 4;
    const int row0 = blockIdx.y * 128, col0 = blockIdx.x * 128;
    const int lrow = tid >> 1, lk = (tid & 1) * 8;

    float acc[8][8];
#pragma unroll
    for (int i = 0; i < 8; i++)
#pragma unroll
        for (int j = 0; j < 8; j++) acc[i][j] = 0.f;

    const float* Ap = A + (size_t)(row0 + lrow) * K + lk;
    const float* Wp = W + (size_t)(col0 + lrow) * K + lk;

    for (int k0 = 0; k0 < K; k0 += 16) {
        float4 a0 = *(const float4*)(Ap + k0);
        float4 a1 = *(const float4*)(Ap + k0 + 4);
        float4 w0 = *(const float4*)(Wp + k0);
        float4 w1 = *(const float4*)(Wp + k0 + 4);
        __syncthreads();
        As[lk + 0][lrow] = a0.x; As[lk + 1][lrow] = a0.y;
        As[lk + 2][lrow] = a0.z; As[lk + 3][lrow] = a0.w;
        As[lk + 4][lrow] = a1.x; As[lk + 5][lrow] = a1.y;
        As[lk + 6][lrow] = a1.z; As[lk + 7][lrow] = a1.w;
        Ws[lk + 0][lrow] = w0.x; Ws[lk + 1][lrow] = w0.y;
        Ws[lk + 2][lrow] = w0.z; Ws[lk + 3][lrow] = w0.w;
        Ws[lk + 4][lrow] = w1.x; Ws[lk + 5][lrow] = w1.y;
        Ws[lk + 6][lrow] = w1.z; Ws[lk + 7][lrow] = w1.w;
        __syncthreads();
#pragma unroll
        for (int kk = 0; kk < 16; kk++) {
            float a[8], bb[8];
#pragma unroll
            for (int i = 0; i < 8; i++) a[i] = As[kk][ty * 8 + i];
#pragma unroll
            for (int j = 0; j < 8; j++) bb[j] = Ws[kk][tx * 8 + j];
#pragma unroll
            for (int i = 0; i < 8; i++)
#pragma unroll
                for (int j = 0; j < 8; j++)
                    acc[i][j] = fmaf(a[i], bb[j], acc[i][j]);
        }
    }

#pragma unroll
    for (int i = 0; i < 8; i++) {
        int row = row0 + ty * 8 + i;
#pragma unroll
        for (int j = 0; j < 8; j++) {
            int col = col0 + tx * 8 + j;
            float v = acc[i][j];
            if (bias) v += bias[col];
            if (relu) v = fmaxf(v, 0.f);
            if (resid) v += resid[(size_t)row * N + col];
            C[(size_t)row * N + col] = v;
        }
    }
}

// ---------------------------------------------------------------------------
// Bucket kernel: for each (bh, round, t): rotated[j] = sum_f qk[t,f]*rot[f,r,j],
// bucket = first-occurrence argmax of [rotated, -rotated].
// grid (T/256, NH, BH), 256 threads.
// ---------------------------------------------------------------------------
__global__ __launch_bounds__(256) void bucket_k(
    const float* __restrict__ qk, const float* __restrict__ rot,
    int* __restrict__ bkt)
{
    __shared__ float rs[64][32];
    const int bh = blockIdx.z, r = blockIdx.y;
    const int t = blockIdx.x * 256 + threadIdx.x;
    for (int i = threadIdx.x; i < 64 * 32; i += 256) {
        int f = i >> 5, j = i & 31;
        rs[f][j] = rot[(f * NH + r) * 32 + j];
    }
    __syncthreads();
    const int b = bh >> 3, h = bh & 7;
    const float* q = qk + ((size_t)(b * TT + t)) * DD + h * DHH;
    float qv[64];
#pragma unroll
    for (int f4 = 0; f4 < 16; f4++) {
        float4 tmp = ((const float4*)q)[f4];
        qv[f4 * 4 + 0] = tmp.x; qv[f4 * 4 + 1] = tmp.y;
        qv[f4 * 4 + 2] = tmp.z; qv[f4 * 4 + 3] = tmp.w;
    }
    float rv[32];
#pragma unroll
    for (int j = 0; j < 32; j++) rv[j] = 0.f;
    for (int f = 0; f < 64; f++) {
        float qf = qv[f];
#pragma unroll
        for (int j = 0; j < 32; j++) rv[j] = fmaf(qf, rs[f][j], rv[j]);
    }
    float best = rv[0];
    int bi = 0;
#pragma unroll
    for (int j = 1; j < 32; j++) { if (rv[j] > best) { best = rv[j]; bi = j; } }
#pragma unroll
    for (int j = 0; j < 32; j++) { float v = -rv[j]; if (v > best) { best = v; bi = 32 + j; } }
    bkt[((size_t)bh * NH + r) * TT + t] = bi;
}

// ---------------------------------------------------------------------------
// Stable counting sort by bucket per (bh, round). 64 threads (one per bucket).
// Reproduces argsort(bucket*T + t): ascending (bucket, t).
// st[bh][r*T + slot] = original t.
// ---------------------------------------------------------------------------
__global__ __launch_bounds__(64) void sort_k(
    const int* __restrict__ bkt, int* __restrict__ st)
{
    __shared__ int lb[TT];
    __shared__ int cnt[64];
    const int r = blockIdx.x, bh = blockIdx.y;
    const int* src = bkt + ((size_t)bh * NH + r) * TT;
    for (int t = threadIdx.x; t < TT; t += 64) lb[t] = src[t];
    __syncthreads();
    const int b = threadIdx.x;
    int c = 0;
    for (int t = 0; t < TT; t++) c += (lb[t] == b) ? 1 : 0;
    cnt[b] = c;
    __syncthreads();
    if (threadIdx.x == 0) {
        int s = 0;
        for (int i = 0; i < 64; i++) { int v = cnt[i]; cnt[i] = s; s += v; }
    }
    __syncthreads();
    int pos = cnt[b];
    int* dst = st + (size_t)bh * (NH * TT) + (size_t)r * TT;
    for (int t = 0; t < TT; t++) {
        if (lb[t] == b) { dst[pos] = t; pos++; }
    }
}

// ---------------------------------------------------------------------------
// Attention per (bh, chunk): gather sorted q/k/v, normalize k, dots 64x128,
// self-mask, softmax+lse, PV, scatter by original t.
// grid (NC, BH), 256 threads. LDS ~114 KB -> 1 block/CU.
// ---------------------------------------------------------------------------
__global__ __launch_bounds__(256) void attn_k(
    const float* __restrict__ qk, const float* __restrict__ vbuf,
    const int* __restrict__ st, float* __restrict__ obuf,
    float* __restrict__ lseb)
{
    __shared__ float qs[64][64];
    __shared__ float ks[128][64];
    __shared__ float vs[128][64];
    __shared__ float ps[64][128];
    __shared__ float lse_s[64];
    __shared__ int tq[64];
    __shared__ int tk[128];

    const int c = blockIdx.x;
    const int bh = blockIdx.y;
    const int b = bh >> 3, h = bh & 7;
    const int tid = threadIdx.x;
    const int* stb = st + (size_t)bh * (NH * TT);

    if (tid < 64) {
        int t = stb[c * 64 + tid];
        tq[tid] = t;
        tk[tid] = t;
    } else if (tid < 128) {
        int cp = (c + NC - 1) & (NC - 1);
        tk[tid] = stb[cp * 64 + (tid - 64)];
    }
    __syncthreads();

    {   // load q: 64 rows x 64, 16 floats/thread
        int row = tid >> 2, col = (tid & 3) * 16;
        const float4* s4 = (const float4*)(qk + ((size_t)(b * TT + tq[row])) * DD + h * DHH + col);
        float4* d4 = (float4*)&qs[row][col];
        d4[0] = s4[0]; d4[1] = s4[1]; d4[2] = s4[2]; d4[3] = s4[3];
    }
    {   // load k,v: 128 rows x 64, 32 floats/thread each
        int row = tid >> 1, col = (tid & 1) * 32;
        int t = tk[row];
        const float4* ksrc = (const float4*)(qk + ((size_t)(b * TT + t)) * DD + h * DHH + col);
        const float4* vsrc = (const float4*)(vbuf + ((size_t)(b * TT + t)) * DD + h * DHH + col);
        float4* kd = (float4*)&ks[row][col];
        float4* vd = (float4*)&vs[row][col];
#pragma unroll
        for (int q = 0; q < 8; q++) { kd[q] = ksrc[q]; vd[q] = vsrc[q]; }
    }
    __syncthreads();

    if (tid < 128) {  // normalize k rows
        float ssum = 0.f;
#pragma unroll
        for (int f = 0; f < 64; f++) { float kv = ks[tid][f]; ssum = fmaf(kv, kv, ssum); }
        float inv = 1.0f / fmaxf(sqrtf(ssum), 1e-12f);
#pragma unroll
        for (int f = 0; f < 64; f++) ks[tid][f] *= inv;
    }
    __syncthreads();

    {   // dots
        int i = tid & 63, p = tid >> 6;
        float qreg[64];
#pragma unroll
        for (int f = 0; f < 64; f++) qreg[f] = qs[i][f];
        int ti = tq[i];
        for (int jj = 0; jj < 32; jj++) {
            int j = p * 32 + jj;
            float d = 0.f;
#pragma unroll
            for (int f = 0; f < 64; f++) d = fmaf(qreg[f], ks[j][f], d);
            d *= 0.125f;
            if (ti == tk[j]) d = -5e4f;
            ps[i][j] = d;
        }
    }
    __syncthreads();

    if (tid < 64) {  // row softmax + lse
        float m = -INFINITY;
#pragma unroll
        for (int j = 0; j < 128; j++) m = fmaxf(m, ps[tid][j]);
        float ssum = 0.f;
        for (int j = 0; j < 128; j++) ssum += expf(ps[tid][j] - m);
        float inv = 1.0f / ssum;
        lse_s[tid] = m + logf(ssum);
        for (int j = 0; j < 128; j++) ps[tid][j] = expf(ps[tid][j] - m) * inv;
    }
    __syncthreads();

    {   // PV + scatter
        int i = tid & 63, p = tid >> 6;
        float acc[16];
#pragma unroll
        for (int q = 0; q < 16; q++) acc[q] = 0.f;
        for (int j = 0; j < 128; j++) {
            float pj = ps[i][j];
#pragma unroll
            for (int q = 0; q < 16; q++) acc[q] = fmaf(pj, vs[j][p * 16 + q], acc[q]);
        }
        int r = c >> 6;
        int t = tq[i];
        float* dst = obuf + (((size_t)bh * NH + r) * TT + t) * DHH + p * 16;
#pragma unroll
        for (int q = 0; q < 16; q++) dst[q] = acc[q];
        if (p == 0) lseb[((size_t)bh * NH + r) * TT + t] = lse_s[i];
    }
}

// ---------------------------------------------------------------------------
// Combine rounds: w_r = softmax over rounds of lse; att = sum_r w_r * o_r.
// One thread per (bh,t,d). Writes merged-head layout (B,T,D).
// ---------------------------------------------------------------------------
__global__ __launch_bounds__(256) void combine_k(
    const float* __restrict__ obuf, const float* __restrict__ lseb,
    float* __restrict__ att)
{
    int idx = blockIdx.x * 256 + threadIdx.x;
    int d = idx & 63;
    int t = (idx >> 6) & (TT - 1);
    int bh = idx >> 18;
    float l0 = lseb[((size_t)bh * NH + 0) * TT + t];
    float l1 = lseb[((size_t)bh * NH + 1) * TT + t];
    float l2 = lseb[((size_t)bh * NH + 2) * TT + t];
    float l3 = lseb[((size_t)bh * NH + 3) * TT + t];
    float m = fmaxf(fmaxf(l0, l1), fmaxf(l2, l3));
    float e0 = expf(l0 - m), e1 = expf(l1 - m), e2 = expf(l2 - m), e3 = expf(l3 - m);
    float inv = 1.0f / (e0 + e1 + e2 + e3);
    float o0 = obuf[(((size_t)bh * NH + 0) * TT + t) * DHH + d];
    float o1 = obuf[(((size_t)bh * NH + 1) * TT + t) * DHH + d];
    float o2 = obuf[(((size_t)bh * NH + 2) * TT + t) * DHH + d];
    float o3 = obuf[(((size_t)bh * NH + 3) * TT + t) * DHH + d];
    float o = (e0 * o0 + e1 * o1 + e2 * o2 + e3 * o3) * inv;
    int b = bh >> 3, h = bh & 7;
    att[((size_t)(b * TT + t)) * DD + h * DHH + d] = o;
}

// ---------------------------------------------------------------------------
// LayerNorm over D=512. One wave per row, 8 floats/lane.
// ---------------------------------------------------------------------------
__global__ __launch_bounds__(64) void ln_k(
    const float* __restrict__ in, const float* __restrict__ g,
    const float* __restrict__ be, float* __restrict__ out)
{
    const int row = blockIdx.x;
    const int tid = threadIdx.x;
    const float* x = in + (size_t)row * DD;
    float4 a = *(const float4*)(x + tid * 8);
    float4 b = *(const float4*)(x + tid * 8 + 4);
    float s = a.x + a.y + a.z + a.w + b.x + b.y + b.z + b.w;
#pragma unroll
    for (int o = 32; o >= 1; o >>= 1) s += __shfl_xor(s, o, 64);
    float mean = s * (1.0f / 512.0f);
    float dx0 = a.x - mean, dx1 = a.y - mean, dx2 = a.z - mean, dx3 = a.w - mean;
    float dx4 = b.x - mean, dx5 = b.y - mean, dx6 = b.z - mean, dx7 = b.w - mean;
    float ss = dx0 * dx0 + dx1 * dx1 + dx2 * dx2 + dx3 * dx3 +
               dx4 * dx4 + dx5 * dx5 + dx6 * dx6 + dx7 * dx7;
#pragma unroll
    for (int o = 32; o >= 1; o >>= 1) ss += __shfl_xor(ss, o, 64);
    float var = ss * (1.0f / 512.0f);
    float inv = 1.0f / sqrtf(var + 1e-6f);
    float* y = out + (size_t)row * DD;
    const float* gp = g + tid * 8;
    const float* bp = be + tid * 8;
    y[tid * 8 + 0] = dx0 * inv * gp[0] + bp[0];
    y[tid * 8 + 1] = dx1 * inv * gp[1] + bp[1];
    y[tid * 8 + 2] = dx2 * inv * gp[2] + bp[2];
    y[tid * 8 + 3] = dx3 * inv * gp[3] + bp[3];
    y[tid * 8 + 4] = dx4 * inv * gp[4] + bp[4];
    y[tid * 8 + 5] = dx5 * inv * gp[5] + bp[5];
    y[tid * 8 + 6] = dx6 * inv * gp[6] + bp[6];
    y[tid * 8 + 7] = dx7 * inv * gp[7] + bp[7];
}

// ---------------------------------------------------------------------------
extern "C" void kernel_launch(void* const* d_in, const int* in_sizes, int n_in,
                              void* d_out, int out_size, void* d_ws, size_t ws_size,
                              hipStream_t stream)
{
    const float* src  = (const float*)d_in[0];
    const float* rots = (const float*)d_in[1];
    const float* Wqk  = (const float*)d_in[2];
    const float* Wv   = (const float*)d_in[3];
    const float* Wout = (const float*)d_in[4];
    const float* bout = (const float*)d_in[5];
    const float* W1   = (const float*)d_in[6];
    const float* b1   = (const float*)d_in[7];
    const float* W2   = (const float*)d_in[8];
    const float* b2   = (const float*)d_in[9];
    const float* g2   = (const float*)d_in[10];
    const float* be2  = (const float*)d_in[11];
    const float* gf   = (const float*)d_in[12];
    const float* bf   = (const float*)d_in[13];
    float* out = (float*)d_out;

    // workspace layout (bytes)
    char* w = (char*)d_ws;
    const size_t SZ_XD = (size_t)MROWS * DD * 4;          // 33.5 MB
    float* x    = (float*)(w);                            // current activations
    float* qkb  = (float*)(w + SZ_XD);                    // qk / also reused for att, yff
    float* vb   = (float*)(w + 2 * SZ_XD);                // v / reused for yff
    float* big  = (float*)(w + 3 * SZ_XD);                // h1 (16384x2048) | obuf (32x4x4096x64)
    char*  tail = w + 3 * SZ_XD + (size_t)MROWS * DFFN * 4;
    int*   bkt  = (int*)(tail);                           // 2 MB
    int*   st   = (int*)(tail + (size_t)BHH * NH * TT * 4);
    float* lseb = (float*)(tail + 2 * (size_t)BHH * NH * TT * 4);

    hipMemcpyAsync(x, src, SZ_XD, hipMemcpyDeviceToDevice, stream);

    for (int i = 0; i < LLAY; i++) {
        const float* Wqk_i = Wqk + (size_t)i * DD * DD;
        const float* Wv_i  = Wv  + (size_t)i * DD * DD;
        const float* Wout_i= Wout+ (size_t)i * DD * DD;
        const float* bout_i= bout+ (size_t)i * DD;
        const float* W1_i  = W1  + (size_t)i * DFFN * DD;
        const float* b1_i  = b1  + (size_t)i * DFFN;
        const float* W2_i  = W2  + (size_t)i * DD * DFFN;
        const float* b2_i  = b2  + (size_t)i * DD;
        const float* g2_i  = g2  + (size_t)i * DD;
        const float* be2_i = be2 + (size_t)i * DD;
        const float* rot_i = rots + (size_t)i * DHH * NH * 32;

        // qk = x @ Wqk^T ; v = x @ Wv^T
        gemm_k<<<dim3(4, 128), 256, 0, stream>>>(x, Wqk_i, nullptr, nullptr, qkb,
                                                 MROWS, DD, DD, 0);
        gemm_k<<<dim3(4, 128), 256, 0, stream>>>(x, Wv_i, nullptr, nullptr, vb,
                                                 MROWS, DD, DD, 0);
        // buckets + sort
        bucket_k<<<dim3(16, NH, BHH), 256, 0, stream>>>(qkb, rot_i, bkt);
        sort_k<<<dim3(NH, BHH), 64, 0, stream>>>(bkt, st);
        // chunked attention (obuf = big)
        attn_k<<<dim3(NC, BHH), 256, 0, stream>>>(qkb, vb, st, big, lseb);
        // combine rounds -> att (write into qkb, which is dead now)
        combine_k<<<(BHH * TT * DHH) / 256, 256, 0, stream>>>(big, lseb, qkb);
        // x = x + att @ Wout^T + bout   (in-place on x)
        gemm_k<<<dim3(4, 128), 256, 0, stream>>>(qkb, Wout_i, bout_i, x, x,
                                                 MROWS, DD, DD, 0);
        // h1 = relu(x @ W1^T + b1)
        gemm_k<<<dim3(16, 128), 256, 0, stream>>>(x, W1_i, b1_i, nullptr, big,
                                                  MROWS, DFFN, DD, 1);
        // yff = x + h1 @ W2^T + b2 -> vb
        gemm_k<<<dim3(4, 128), 256, 0, stream>>>(big, W2_i, b2_i, x, vb,
                                                 MROWS, DD, DFFN, 0);
        // x = LN(yff)
        ln_k<<<MROWS, 64, 0, stream>>>(vb, g2_i, be2_i, x);
    }
    // final LN -> out
    ln_k<<<MROWS, 64, 0, stream>>>(x, gf, bf, out);
}

// Round 2
// 10040.403 us; speedup vs baseline: 1.2473x; 1.2473x over previous
//
#include <hip/hip_runtime.h>
#include <math.h>

#define BQ    4
#define TT    4096
#define DD    512
#define HH    8
#define DHH   64
#define NH    4
#define BSZ   64
#define NBK   64
#define LLAY  4
#define DFFN  2048
#define BHH   32          // B*H
#define NC    256         // chunks per bh (NH*NB)
#define MROWS 16384       // B*T

// ---------------------------------------------------------------------------
// Generic fp32 GEMM: C = op(A @ W^T + bias) [+ resid]
// ---------------------------------------------------------------------------
__global__ __launch_bounds__(256) void gemm_k(
    const float* __restrict__ A, const float* __restrict__ W,
    const float* __restrict__ bias, const float* __restrict__ resid,
    float* __restrict__ C, int M, int N, int K, int relu)
{
    __shared__ float As[16][128];
    __shared__ float Ws[16][128];
    const int tid = threadIdx.x;
    const int tx = tid & 15, ty = tid >> 4;
    const int row0 = blockIdx.y * 128, col0 = blockIdx.x * 128;
    const int lrow = tid >> 1, lk = (tid & 1) * 8;

    float acc[8][8];
#pragma unroll
    for (int i = 0; i < 8; i++)
#pragma unroll
        for (int j = 0; j < 8; j++) acc[i][j] = 0.f;

    const float* Ap = A + (size_t)(row0 + lrow) * K + lk;
    const float* Wp = W + (size_t)(col0 + lrow) * K + lk;

    for (int k0 = 0; k0 < K; k0 += 16) {
        float4 a0 = *(const float4*)(Ap + k0);
        float4 a1 = *(const float4*)(Ap + k0 + 4);
        float4 w0 = *(const float4*)(Wp + k0);
        float4 w1 = *(const float4*)(Wp + k0 + 4);
        __syncthreads();
        As[lk + 0][lrow] = a0.x; As[lk + 1][lrow] = a0.y;
        As[lk + 2][lrow] = a0.z; As[lk + 3][lrow] = a0.w;
        As[lk + 4][lrow] = a1.x; As[lk + 5][lrow] = a1.y;
        As[lk + 6][lrow] = a1.z; As[lk + 7][lrow] = a1.w;
        Ws[lk + 0][lrow] = w0.x; Ws[lk + 1][lrow] = w0.y;
        Ws[lk + 2][lrow] = w0.z; Ws[lk + 3][lrow] = w0.w;
        Ws[lk + 4][lrow] = w1.x; Ws[lk + 5][lrow] = w1.y;
        Ws[lk + 6][lrow] = w1.z; Ws[lk + 7][lrow] = w1.w;
        __syncthreads();
#pragma unroll
        for (int kk = 0; kk < 16; kk++) {
            float a[8], bb[8];
#pragma unroll
            for (int i = 0; i < 8; i++) a[i] = As[kk][ty * 8 + i];
#pragma unroll
            for (int j = 0; j < 8; j++) bb[j] = Ws[kk][tx * 8 + j];
#pragma unroll
            for (int i = 0; i < 8; i++)
#pragma unroll
                for (int j = 0; j < 8; j++)
                    acc[i][j] = fmaf(a[i], bb[j], acc[i][j]);
        }
    }

#pragma unroll
    for (int i = 0; i < 8; i++) {
        int row = row0 + ty * 8 + i;
#pragma unroll
        for (int j = 0; j < 8; j++) {
            int col = col0 + tx * 8 + j;
            float v = acc[i][j];
            if (bias) v += bias[col];
            if (relu) v = fmaxf(v, 0.f);
            if (resid) v += resid[(size_t)row * N + col];
            C[(size_t)row * N + col] = v;
        }
    }
}

// ---------------------------------------------------------------------------
// Bucket kernel (unchanged)
// ---------------------------------------------------------------------------
__global__ __launch_bounds__(256) void bucket_k(
    const float* __restrict__ qk, const float* __restrict__ rot,
    int* __restrict__ bkt)
{
    __shared__ float rs[64][32];
    const int bh = blockIdx.z, r = blockIdx.y;
    const int t = blockIdx.x * 256 + threadIdx.x;
    for (int i = threadIdx.x; i < 64 * 32; i += 256) {
        int f = i >> 5, j = i & 31;
        rs[f][j] = rot[(f * NH + r) * 32 + j];
    }
    __syncthreads();
    const int b = bh >> 3, h = bh & 7;
    const float* q = qk + ((size_t)(b * TT + t)) * DD + h * DHH;
    float qv[64];
#pragma unroll
    for (int f4 = 0; f4 < 16; f4++) {
        float4 tmp = ((const float4*)q)[f4];
        qv[f4 * 4 + 0] = tmp.x; qv[f4 * 4 + 1] = tmp.y;
        qv[f4 * 4 + 2] = tmp.z; qv[f4 * 4 + 3] = tmp.w;
    }
    float rv[32];
#pragma unroll
    for (int j = 0; j < 32; j++) rv[j] = 0.f;
    for (int f = 0; f < 64; f++) {
        float qf = qv[f];
#pragma unroll
        for (int j = 0; j < 32; j++) rv[j] = fmaf(qf, rs[f][j], rv[j]);
    }
    float best = rv[0];
    int bi = 0;
#pragma unroll
    for (int j = 1; j < 32; j++) { if (rv[j] > best) { best = rv[j]; bi = j; } }
#pragma unroll
    for (int j = 0; j < 32; j++) { float v = -rv[j]; if (v > best) { best = v; bi = 32 + j; } }
    bkt[((size_t)bh * NH + r) * TT + t] = bi;
}

// ---------------------------------------------------------------------------
// Stable counting sort by bucket per (bh, round). (unchanged)
// ---------------------------------------------------------------------------
__global__ __launch_bounds__(64) void sort_k(
    const int* __restrict__ bkt, int* __restrict__ st)
{
    __shared__ int lb[TT];
    __shared__ int cnt[64];
    const int r = blockIdx.x, bh = blockIdx.y;
    const int* src = bkt + ((size_t)bh * NH + r) * TT;
    for (int t = threadIdx.x; t < TT; t += 64) lb[t] = src[t];
    __syncthreads();
    const int b = threadIdx.x;
    int c = 0;
    for (int t = 0; t < TT; t++) c += (lb[t] == b) ? 1 : 0;
    cnt[b] = c;
    __syncthreads();
    if (threadIdx.x == 0) {
        int s = 0;
        for (int i = 0; i < 64; i++) { int v = cnt[i]; cnt[i] = s; s += v; }
    }
    __syncthreads();
    int pos = cnt[b];
    int* dst = st + (size_t)bh * (NH * TT) + (size_t)r * TT;
    for (int t = 0; t < TT; t++) {
        if (lb[t] == b) { dst[pos] = t; pos++; }
    }
}

// ---------------------------------------------------------------------------
// Attention v2: swizzled LDS (conflict-free), q==k rows (no qs), register
// probs + in-wave softmax, register PV + reduce-scatter butterfly.
// Per block: one (bh, chunk). 256 thr / 4 waves. LDS ~66KB -> 2 blocks/CU.
// Lane mapping: wave w owns q-rows [w*16, w*16+16); lane = ig*8+p;
// lane handles rows {i0, i0+1} (i0 = w*16+ig*2) x j-range [p*16, p*16+16).
// Swizzle: elem (row,f) at col (f + 4*(row&15) + 8*(row>>5)) & 63.
// ---------------------------------------------------------------------------
__global__ __launch_bounds__(256, 2) void attn_k(
    const float* __restrict__ qk, const float* __restrict__ vbuf,
    const int* __restrict__ st, float* __restrict__ obuf,
    float* __restrict__ lseb)
{
    __shared__ float ks[128 * 64];
    __shared__ float vs[128 * 64];
    __shared__ float invn[128];
    __shared__ int   tks[128];

    const int c = blockIdx.x;
    const int bh = blockIdx.y;
    const int b = bh >> 3, h = bh & 7;
    const int tid = threadIdx.x;
    const int* stb = st + (size_t)bh * (NH * TT);

    if (tid < 128) {
        int cc = (tid < 64) ? c : ((c + NC - 1) & (NC - 1));
        tks[tid] = stb[cc * 64 + (tid & 63)];
    }
    __syncthreads();

    {   // stage k,v (swizzled) + inv norms (norm from registers + pair shfl)
        const int row = tid >> 1, c0 = (tid & 1) * 32;
        const int t = tks[row];
        const float4* kg = (const float4*)(qk + ((size_t)(b * TT + t)) * DD + h * DHH + c0);
        const float4* vg = (const float4*)(vbuf + ((size_t)(b * TT + t)) * DD + h * DHH + c0);
        float4 kv[8], vv[8];
        float ss = 0.f;
#pragma unroll
        for (int q = 0; q < 8; q++) {
            kv[q] = kg[q]; vv[q] = vg[q];
            ss += kv[q].x * kv[q].x + kv[q].y * kv[q].y
                + kv[q].z * kv[q].z + kv[q].w * kv[q].w;
        }
        ss += __shfl_xor(ss, 1);
        if ((tid & 1) == 0) invn[row] = 1.0f / fmaxf(sqrtf(ss), 1e-12f);
        const int sh = ((row & 15) << 2) + ((row >> 5) << 3);
#pragma unroll
        for (int q = 0; q < 8; q++) {
            int col = (c0 + 4 * q + sh) & 63;
            *(float4*)&ks[row * 64 + col] = kv[q];
            *(float4*)&vs[row * 64 + col] = vv[q];
        }
    }
    __syncthreads();

    const int lane = tid & 63;
    const int wv   = tid >> 6;
    const int ig   = lane >> 3;
    const int p    = lane & 7;
    const int i0   = wv * 16 + ig * 2;
    const int i1   = i0 + 1;
    const int jb   = p * 16;
    const int rbase = (p >> 1) << 3;                     // k/v row-shift part
    const int shq0 = ((i0 & 15) << 2) + ((i0 >> 5) << 3);
    const int shq1 = ((i1 & 15) << 2) + ((i1 >> 5) << 3);

    // ---- dots: dt[r][jj] = q_{i0+r} . k_{jb+jj} ----
    float dt0[16], dt1[16];
#pragma unroll
    for (int q = 0; q < 16; q++) { dt0[q] = 0.f; dt1[q] = 0.f; }

#pragma unroll 4
    for (int f4 = 0; f4 < 16; f4++) {
        const float4 q0 = *(const float4*)&ks[i0 * 64 + ((4 * f4 + shq0) & 63)];
        const float4 q1 = *(const float4*)&ks[i1 * 64 + ((4 * f4 + shq1) & 63)];
#pragma unroll
        for (int jj = 0; jj < 16; jj++) {
            const int j = jb + jj;
            const float4 kv = *(const float4*)&ks[j * 64 + ((4 * (f4 + jj) + rbase) & 63)];
            dt0[jj] = fmaf(q0.x, kv.x, dt0[jj]);
            dt0[jj] = fmaf(q0.y, kv.y, dt0[jj]);
            dt0[jj] = fmaf(q0.z, kv.z, dt0[jj]);
            dt0[jj] = fmaf(q0.w, kv.w, dt0[jj]);
            dt1[jj] = fmaf(q1.x, kv.x, dt1[jj]);
            dt1[jj] = fmaf(q1.y, kv.y, dt1[jj]);
            dt1[jj] = fmaf(q1.z, kv.z, dt1[jj]);
            dt1[jj] = fmaf(q1.w, kv.w, dt1[jj]);
        }
    }

    // ---- scale, self-mask, softmax (8-lane groups via shfl_xor 1/2/4) ----
    const int ti0 = tks[i0], ti1 = tks[i1];
    float m0 = -INFINITY, m1 = -INFINITY;
#pragma unroll
    for (int jj = 0; jj < 16; jj++) {
        const int j = jb + jj;
        const float sc = invn[j] * 0.125f;
        const int tkj = tks[j];
        float d0 = dt0[jj] * sc; if (ti0 == tkj) d0 = -5e4f;
        float d1 = dt1[jj] * sc; if (ti1 == tkj) d1 = -5e4f;
        dt0[jj] = d0; dt1[jj] = d1;
        m0 = fmaxf(m0, d0); m1 = fmaxf(m1, d1);
    }
    m0 = fmaxf(m0, __shfl_xor(m0, 1));
    m0 = fmaxf(m0, __shfl_xor(m0, 2));
    m0 = fmaxf(m0, __shfl_xor(m0, 4));
    m1 = fmaxf(m1, __shfl_xor(m1, 1));
    m1 = fmaxf(m1, __shfl_xor(m1, 2));
    m1 = fmaxf(m1, __shfl_xor(m1, 4));
    float s0 = 0.f, s1 = 0.f;
#pragma unroll
    for (int jj = 0; jj < 16; jj++) {
        float e0 = expf(dt0[jj] - m0); dt0[jj] = e0; s0 += e0;
        float e1 = expf(dt1[jj] - m1); dt1[jj] = e1; s1 += e1;
    }
    s0 += __shfl_xor(s0, 1); s0 += __shfl_xor(s0, 2); s0 += __shfl_xor(s0, 4);
    s1 += __shfl_xor(s1, 1); s1 += __shfl_xor(s1, 2); s1 += __shfl_xor(s1, 4);
    const float lse0 = m0 + logf(s0), lse1 = m1 + logf(s1);
    const float is0 = 1.0f / s0, is1 = 1.0f / s1;
#pragma unroll
    for (int jj = 0; jj < 16; jj++) { dt0[jj] *= is0; dt1[jj] *= is1; }

    // ---- PV: acc[r][f] += prob[r][jj] * v[jb+jj][f] (full unroll, static) ----
    float a0[64], a1[64];
#pragma unroll
    for (int q = 0; q < 64; q++) { a0[q] = 0.f; a1[q] = 0.f; }
#pragma unroll
    for (int jj = 0; jj < 16; jj++) {
        const int j = jb + jj;
        const float p0 = dt0[jj], p1 = dt1[jj];
#pragma unroll
        for (int f4 = 0; f4 < 16; f4++) {
            const float4 vv = *(const float4*)&vs[j * 64 + ((4 * (f4 + jj) + rbase) & 63)];
            a0[4 * f4 + 0] = fmaf(p0, vv.x, a0[4 * f4 + 0]);
            a0[4 * f4 + 1] = fmaf(p0, vv.y, a0[4 * f4 + 1]);
            a0[4 * f4 + 2] = fmaf(p0, vv.z, a0[4 * f4 + 2]);
            a0[4 * f4 + 3] = fmaf(p0, vv.w, a0[4 * f4 + 3]);
            a1[4 * f4 + 0] = fmaf(p1, vv.x, a1[4 * f4 + 0]);
            a1[4 * f4 + 1] = fmaf(p1, vv.y, a1[4 * f4 + 1]);
            a1[4 * f4 + 2] = fmaf(p1, vv.z, a1[4 * f4 + 2]);
            a1[4 * f4 + 3] = fmaf(p1, vv.w, a1[4 * f4 + 3]);
        }
    }

    // ---- reduce-scatter over the 8-lane group: lane p ends with f in [8p,8p+8) ----
    const bool k4 = (p & 4) != 0;
    float r0[32], r1[32];
#pragma unroll
    for (int q = 0; q < 32; q++) {
        float mn0 = k4 ? a0[q + 32] : a0[q];
        float ot0 = k4 ? a0[q] : a0[q + 32];
        r0[q] = mn0 + __shfl_xor(ot0, 4);
        float mn1 = k4 ? a1[q + 32] : a1[q];
        float ot1 = k4 ? a1[q] : a1[q + 32];
        r1[q] = mn1 + __shfl_xor(ot1, 4);
    }
    const bool k2 = (p & 2) != 0;
    float u0[16], u1[16];
#pragma unroll
    for (int q = 0; q < 16; q++) {
        float mn0 = k2 ? r0[q + 16] : r0[q];
        float ot0 = k2 ? r0[q] : r0[q + 16];
        u0[q] = mn0 + __shfl_xor(ot0, 2);
        float mn1 = k2 ? r1[q + 16] : r1[q];
        float ot1 = k2 ? r1[q] : r1[q + 16];
        u1[q] = mn1 + __shfl_xor(ot1, 2);
    }
    const bool k1 = (p & 1) != 0;
    float w0[8], w1[8];
#pragma unroll
    for (int q = 0; q < 8; q++) {
        float mn0 = k1 ? u0[q + 8] : u0[q];
        float ot0 = k1 ? u0[q] : u0[q + 8];
        w0[q] = mn0 + __shfl_xor(ot0, 1);
        float mn1 = k1 ? u1[q + 8] : u1[q];
        float ot1 = k1 ? u1[q] : u1[q + 8];
        w1[q] = mn1 + __shfl_xor(ot1, 1);
    }

    const int r = c >> 6;
    const size_t ob0 = (((size_t)bh * NH + r) * TT + ti0) * DHH + p * 8;
    const size_t ob1 = (((size_t)bh * NH + r) * TT + ti1) * DHH + p * 8;
    *(float4*)(obuf + ob0)     = make_float4(w0[0], w0[1], w0[2], w0[3]);
    *(float4*)(obuf + ob0 + 4) = make_float4(w0[4], w0[5], w0[6], w0[7]);
    *(float4*)(obuf + ob1)     = make_float4(w1[0], w1[1], w1[2], w1[3]);
    *(float4*)(obuf + ob1 + 4) = make_float4(w1[4], w1[5], w1[6], w1[7]);
    if (p == 0) {
        lseb[((size_t)bh * NH + r) * TT + ti0] = lse0;
        lseb[((size_t)bh * NH + r) * TT + ti1] = lse1;
    }
}

// ---------------------------------------------------------------------------
// Combine rounds (unchanged)
// ---------------------------------------------------------------------------
__global__ __launch_bounds__(256) void combine_k(
    const float* __restrict__ obuf, const float* __restrict__ lseb,
    float* __restrict__ att)
{
    int idx = blockIdx.x * 256 + threadIdx.x;
    int d = idx & 63;
    int t = (idx >> 6) & (TT - 1);
    int bh = idx >> 18;
    float l0 = lseb[((size_t)bh * NH + 0) * TT + t];
    float l1 = lseb[((size_t)bh * NH + 1) * TT + t];
    float l2 = lseb[((size_t)bh * NH + 2) * TT + t];
    float l3 = lseb[((size_t)bh * NH + 3) * TT + t];
    float m = fmaxf(fmaxf(l0, l1), fmaxf(l2, l3));
    float e0 = expf(l0 - m), e1 = expf(l1 - m), e2 = expf(l2 - m), e3 = expf(l3 - m);
    float inv = 1.0f / (e0 + e1 + e2 + e3);
    float o0 = obuf[(((size_t)bh * NH + 0) * TT + t) * DHH + d];
    float o1 = obuf[(((size_t)bh * NH + 1) * TT + t) * DHH + d];
    float o2 = obuf[(((size_t)bh * NH + 2) * TT + t) * DHH + d];
    float o3 = obuf[(((size_t)bh * NH + 3) * TT + t) * DHH + d];
    float o = (e0 * o0 + e1 * o1 + e2 * o2 + e3 * o3) * inv;
    int b = bh >> 3, h = bh & 7;
    att[((size_t)(b * TT + t)) * DD + h * DHH + d] = o;
}

// ---------------------------------------------------------------------------
// LayerNorm over D=512 (unchanged)
// ---------------------------------------------------------------------------
__global__ __launch_bounds__(64) void ln_k(
    const float* __restrict__ in, const float* __restrict__ g,
    const float* __restrict__ be, float* __restrict__ out)
{
    const int row = blockIdx.x;
    const int tid = threadIdx.x;
    const float* x = in + (size_t)row * DD;
    float4 a = *(const float4*)(x + tid * 8);
    float4 b = *(const float4*)(x + tid * 8 + 4);
    float s = a.x + a.y + a.z + a.w + b.x + b.y + b.z + b.w;
#pragma unroll
    for (int o = 32; o >= 1; o >>= 1) s += __shfl_xor(s, o, 64);
    float mean = s * (1.0f / 512.0f);
    float dx0 = a.x - mean, dx1 = a.y - mean, dx2 = a.z - mean, dx3 = a.w - mean;
    float dx4 = b.x - mean, dx5 = b.y - mean, dx6 = b.z - mean, dx7 = b.w - mean;
    float ss = dx0 * dx0 + dx1 * dx1 + dx2 * dx2 + dx3 * dx3 +
               dx4 * dx4 + dx5 * dx5 + dx6 * dx6 + dx7 * dx7;
#pragma unroll
    for (int o = 32; o >= 1; o >>= 1) ss += __shfl_xor(ss, o, 64);
    float var = ss * (1.0f / 512.0f);
    float inv = 1.0f / sqrtf(var + 1e-6f);
    float* y = out + (size_t)row * DD;
    const float* gp = g + tid * 8;
    const float* bp = be + tid * 8;
    y[tid * 8 + 0] = dx0 * inv * gp[0] + bp[0];
    y[tid * 8 + 1] = dx1 * inv * gp[1] + bp[1];
    y[tid * 8 + 2] = dx2 * inv * gp[2] + bp[2];
    y[tid * 8 + 3] = dx3 * inv * gp[3] + bp[3];
    y[tid * 8 + 4] = dx4 * inv * gp[4] + bp[4];
    y[tid * 8 + 5] = dx5 * inv * gp[5] + bp[5];
    y[tid * 8 + 6] = dx6 * inv * gp[6] + bp[6];
    y[tid * 8 + 7] = dx7 * inv * gp[7] + bp[7];
}

// ---------------------------------------------------------------------------
extern "C" void kernel_launch(void* const* d_in, const int* in_sizes, int n_in,
                              void* d_out, int out_size, void* d_ws, size_t ws_size,
                              hipStream_t stream)
{
    const float* src  = (const float*)d_in[0];
    const float* rots = (const float*)d_in[1];
    const float* Wqk  = (const float*)d_in[2];
    const float* Wv   = (const float*)d_in[3];
    const float* Wout = (const float*)d_in[4];
    const float* bout = (const float*)d_in[5];
    const float* W1   = (const float*)d_in[6];
    const float* b1   = (const float*)d_in[7];
    const float* W2   = (const float*)d_in[8];
    const float* b2   = (const float*)d_in[9];
    const float* g2   = (const float*)d_in[10];
    const float* be2  = (const float*)d_in[11];
    const float* gf   = (const float*)d_in[12];
    const float* bf   = (const float*)d_in[13];
    float* out = (float*)d_out;

    // workspace layout (bytes)
    char* w = (char*)d_ws;
    const size_t SZ_XD = (size_t)MROWS * DD * 4;          // 33.5 MB
    float* x    = (float*)(w);                            // current activations
    float* qkb  = (float*)(w + SZ_XD);                    // qk / att
    float* vb   = (float*)(w + 2 * SZ_XD);                // v / yff
    float* big  = (float*)(w + 3 * SZ_XD);                // h1 | obuf
    char*  tail = w + 3 * SZ_XD + (size_t)MROWS * DFFN * 4;
    int*   bkt  = (int*)(tail);
    int*   st   = (int*)(tail + (size_t)BHH * NH * TT * 4);
    float* lseb = (float*)(tail + 2 * (size_t)BHH * NH * TT * 4);

    hipMemcpyAsync(x, src, SZ_XD, hipMemcpyDeviceToDevice, stream);

    for (int i = 0; i < LLAY; i++) {
        const float* Wqk_i = Wqk + (size_t)i * DD * DD;
        const float* Wv_i  = Wv  + (size_t)i * DD * DD;
        const float* Wout_i= Wout+ (size_t)i * DD * DD;
        const float* bout_i= bout+ (size_t)i * DD;
        const float* W1_i  = W1  + (size_t)i * DFFN * DD;
        const float* b1_i  = b1  + (size_t)i * DFFN;
        const float* W2_i  = W2  + (size_t)i * DD * DFFN;
        const float* b2_i  = b2  + (size_t)i * DD;
        const float* g2_i  = g2  + (size_t)i * DD;
        const float* be2_i = be2 + (size_t)i * DD;
        const float* rot_i = rots + (size_t)i * DHH * NH * 32;

        gemm_k<<<dim3(4, 128), 256, 0, stream>>>(x, Wqk_i, nullptr, nullptr, qkb,
                                                 MROWS, DD, DD, 0);
        gemm_k<<<dim3(4, 128), 256, 0, stream>>>(x, Wv_i, nullptr, nullptr, vb,
                                                 MROWS, DD, DD, 0);
        bucket_k<<<dim3(16, NH, BHH), 256, 0, stream>>>(qkb, rot_i, bkt);
        sort_k<<<dim3(NH, BHH), 64, 0, stream>>>(bkt, st);
        attn_k<<<dim3(NC, BHH), 256, 0, stream>>>(qkb, vb, st, big, lseb);
        combine_k<<<(BHH * TT * DHH) / 256, 256, 0, stream>>>(big, lseb, qkb);
        gemm_k<<<dim3(4, 128), 256, 0, stream>>>(qkb, Wout_i, bout_i, x, x,
                                                 MROWS, DD, DD, 0);
        gemm_k<<<dim3(16, 128), 256, 0, stream>>>(x, W1_i, b1_i, nullptr, big,
                                                  MROWS, DFFN, DD, 1);
        gemm_k<<<dim3(4, 128), 256, 0, stream>>>(big, W2_i, b2_i, x, vb,
                                                 MROWS, DD, DFFN, 0);
        ln_k<<<MROWS, 64, 0, stream>>>(vb, g2_i, be2_i, x);
    }
    ln_k<<<MROWS, 64, 0, stream>>>(x, gf, bf, out);
}

// Round 3
// 5817.899 us; speedup vs baseline: 2.1526x; 1.7258x over previous
//
#include <hip/hip_runtime.h>
#include <math.h>

#define TT    4096
#define DD    512
#define HH    8
#define DHH   64
#define NH    4
#define LLAY  4
#define DFFN  2048
#define BHH   32          // B*H
#define NC    256         // chunks per bh (NH*NB)
#define MROWS 16384       // B*T

typedef __attribute__((ext_vector_type(8))) short s16x8;
typedef __attribute__((ext_vector_type(4))) float f32x4;
typedef unsigned short ushort_t;

__device__ __forceinline__ unsigned short f2bf(float f) {
    unsigned u = __float_as_uint(f);
    unsigned r = (u + 0x7FFFu + ((u >> 16) & 1u)) >> 16;
    return (unsigned short)r;
}
__device__ __forceinline__ float bf2f(unsigned short h) {
    return __uint_as_float(((unsigned)h) << 16);
}

// ---------------------------------------------------------------------------
// fp32 GEMM (used only for qk = x @ Wqk^T : argmax-critical path)
// ---------------------------------------------------------------------------
__global__ __launch_bounds__(256) void gemm_k(
    const float* __restrict__ A, const float* __restrict__ W,
    const float* __restrict__ bias, const float* __restrict__ resid,
    float* __restrict__ C, int M, int N, int K, int relu)
{
    __shared__ float As[16][128];
    __shared__ float Ws[16][128];
    const int tid = threadIdx.x;
    const int tx = tid & 15, ty = tid >> 4;
    const int row0 = blockIdx.y * 128, col0 = blockIdx.x * 128;
    const int lrow = tid >> 1, lk = (tid & 1) * 8;

    float acc[8][8];
#pragma unroll
    for (int i = 0; i < 8; i++)
#pragma unroll
        for (int j = 0; j < 8; j++) acc[i][j] = 0.f;

    const float* Ap = A + (size_t)(row0 + lrow) * K + lk;
    const float* Wp = W + (size_t)(col0 + lrow) * K + lk;

    for (int k0 = 0; k0 < K; k0 += 16) {
        float4 a0 = *(const float4*)(Ap + k0);
        float4 a1 = *(const float4*)(Ap + k0 + 4);
        float4 w0 = *(const float4*)(Wp + k0);
        float4 w1 = *(const float4*)(Wp + k0 + 4);
        __syncthreads();
        As[lk + 0][lrow] = a0.x; As[lk + 1][lrow] = a0.y;
        As[lk + 2][lrow] = a0.z; As[lk + 3][lrow] = a0.w;
        As[lk + 4][lrow] = a1.x; As[lk + 5][lrow] = a1.y;
        As[lk + 6][lrow] = a1.z; As[lk + 7][lrow] = a1.w;
        Ws[lk + 0][lrow] = w0.x; Ws[lk + 1][lrow] = w0.y;
        Ws[lk + 2][lrow] = w0.z; Ws[lk + 3][lrow] = w0.w;
        Ws[lk + 4][lrow] = w1.x; Ws[lk + 5][lrow] = w1.y;
        Ws[lk + 6][lrow] = w1.z; Ws[lk + 7][lrow] = w1.w;
        __syncthreads();
#pragma unroll
        for (int kk = 0; kk < 16; kk++) {
            float a[8], bb[8];
#pragma unroll
            for (int i = 0; i < 8; i++) a[i] = As[kk][ty * 8 + i];
#pragma unroll
            for (int j = 0; j < 8; j++) bb[j] = Ws[kk][tx * 8 + j];
#pragma unroll
            for (int i = 0; i < 8; i++)
#pragma unroll
                for (int j = 0; j < 8; j++)
                    acc[i][j] = fmaf(a[i], bb[j], acc[i][j]);
        }
    }

#pragma unroll
    for (int i = 0; i < 8; i++) {
        int row = row0 + ty * 8 + i;
#pragma unroll
        for (int j = 0; j < 8; j++) {
            int col = col0 + tx * 8 + j;
            float v = acc[i][j];
            if (bias) v += bias[col];
            if (relu) v = fmaxf(v, 0.f);
            if (resid) v += resid[(size_t)row * N + col];
            C[(size_t)row * N + col] = v;
        }
    }
}

// ---------------------------------------------------------------------------
// bf16x3 MFMA GEMM: C = op(A @ W^T + bias) [+resid], fp32 accuracy (~1e-5 rel)
// A given as hi/lo bf16 (M,K) row stride lda; W as hi/lo bf16 (N,K) stride K.
// 128x128 tile, BK=32, 4 waves (2x2 of 64x64), 16x16x32 MFMA, x3 products.
// LDS: 4 tiles of 128x32 bf16 (8KB each), XOR-unit-swizzled, staged via
// global_load_lds (linear dest + pre-swizzled source).
// ---------------------------------------------------------------------------
__global__ __launch_bounds__(256) void gemm_bf3_k(
    const ushort_t* __restrict__ Ah, const ushort_t* __restrict__ Al, int lda,
    const ushort_t* __restrict__ Wh, const ushort_t* __restrict__ Wl,
    const float* __restrict__ bias, const float* __restrict__ resid,
    float* __restrict__ outf, ushort_t* __restrict__ outh, ushort_t* __restrict__ outl,
    int M, int N, int K, int relu)
{
    __shared__ __align__(16) ushort_t lds[4 * 128 * 32];   // Ah,Al,Wh,Wl
    const int tid  = threadIdx.x;
    const int lane = tid & 63;
    const int wv   = tid >> 6;
    const int wm   = wv >> 1, wn = wv & 1;
    const int row0 = blockIdx.y * 128, col0 = blockIdx.x * 128;
    const int g    = lane >> 4;

    f32x4 acc[4][4];
#pragma unroll
    for (int mi = 0; mi < 4; mi++)
#pragma unroll
        for (int ni = 0; ni < 4; ni++) acc[mi][ni] = (f32x4)(0.f);

    const int srow0 = wv * 32;                       // rows staged by this wave

    for (int k0 = 0; k0 < K; k0 += 32) {
        __syncthreads();
#pragma unroll
        for (int ii = 0; ii < 2; ii++) {
            const int r   = srow0 + ii * 16 + (lane >> 2);        // row in tile
            const int ug  = (((lane & 3) ^ ((r >> 1) & 3)) << 3); // logical k elem
            const size_t ga = (size_t)(row0 + r) * lda + k0 + ug;
            const size_t gw = (size_t)(col0 + r) * K   + k0 + ug;
            const int lo  = (srow0 + ii * 16) * 32;               // instr base elem
            __builtin_amdgcn_global_load_lds(
                (const __attribute__((address_space(1))) void*)(Ah + ga),
                (__attribute__((address_space(3))) void*)&lds[0 * 4096 + lo], 16, 0, 0);
            __builtin_amdgcn_global_load_lds(
                (const __attribute__((address_space(1))) void*)(Al + ga),
                (__attribute__((address_space(3))) void*)&lds[1 * 4096 + lo], 16, 0, 0);
            __builtin_amdgcn_global_load_lds(
                (const __attribute__((address_space(1))) void*)(Wh + gw),
                (__attribute__((address_space(3))) void*)&lds[2 * 4096 + lo], 16, 0, 0);
            __builtin_amdgcn_global_load_lds(
                (const __attribute__((address_space(1))) void*)(Wl + gw),
                (__attribute__((address_space(3))) void*)&lds[3 * 4096 + lo], 16, 0, 0);
        }
        __syncthreads();

        s16x8 ah[4], al[4], wh[4], wl[4];
#pragma unroll
        for (int mi = 0; mi < 4; mi++) {
            const int m  = wm * 64 + mi * 16 + (lane & 15);
            const int pu = ((g ^ ((m >> 1) & 3)) << 3);
            ah[mi] = *(const s16x8*)&lds[0 * 4096 + m * 32 + pu];
            al[mi] = *(const s16x8*)&lds[1 * 4096 + m * 32 + pu];
            const int n  = wn * 64 + mi * 16 + (lane & 15);
            const int pn = ((g ^ ((n >> 1) & 3)) << 3);
            wh[mi] = *(const s16x8*)&lds[2 * 4096 + n * 32 + pn];
            wl[mi] = *(const s16x8*)&lds[3 * 4096 + n * 32 + pn];
        }
#pragma unroll
        for (int mi = 0; mi < 4; mi++)
#pragma unroll
            for (int ni = 0; ni < 4; ni++) {
                acc[mi][ni] = __builtin_amdgcn_mfma_f32_16x16x32_bf16(ah[mi], wh[ni], acc[mi][ni], 0, 0, 0);
                acc[mi][ni] = __builtin_amdgcn_mfma_f32_16x16x32_bf16(al[mi], wh[ni], acc[mi][ni], 0, 0, 0);
                acc[mi][ni] = __builtin_amdgcn_mfma_f32_16x16x32_bf16(ah[mi], wl[ni], acc[mi][ni], 0, 0, 0);
            }
    }

#pragma unroll
    for (int mi = 0; mi < 4; mi++) {
#pragma unroll
        for (int ni = 0; ni < 4; ni++) {
#pragma unroll
            for (int r = 0; r < 4; r++) {
                const int row = row0 + wm * 64 + mi * 16 + g * 4 + r;
                const int col = col0 + wn * 64 + ni * 16 + (lane & 15);
                float v = acc[mi][ni][r];
                if (bias)  v += bias[col];
                if (relu)  v = fmaxf(v, 0.f);
                if (resid) v += resid[(size_t)row * N + col];
                if (outf)  outf[(size_t)row * N + col] = v;
                if (outh) {
                    unsigned short h = f2bf(v);
                    outh[(size_t)row * N + col] = h;
                    outl[(size_t)row * N + col] = f2bf(v - bf2f(h));
                }
            }
        }
    }
}

// ---------------------------------------------------------------------------
// fp32 -> bf16 hi/lo converter (float4 vectorized); n4 = elems/4
// ---------------------------------------------------------------------------
__global__ __launch_bounds__(256) void cvt_k(
    const float* __restrict__ in, ushort_t* __restrict__ hi,
    ushort_t* __restrict__ lo, int n4)
{
    int i = blockIdx.x * 256 + threadIdx.x;
    if (i >= n4) return;
    float4 v = ((const float4*)in)[i];
    unsigned short h0 = f2bf(v.x), h1 = f2bf(v.y), h2 = f2bf(v.z), h3 = f2bf(v.w);
    ushort4 hv; hv.x = h0; hv.y = h1; hv.z = h2; hv.w = h3;
    ushort4 lv;
    lv.x = f2bf(v.x - bf2f(h0)); lv.y = f2bf(v.y - bf2f(h1));
    lv.z = f2bf(v.z - bf2f(h2)); lv.w = f2bf(v.w - bf2f(h3));
    ((ushort4*)hi)[i] = hv;
    ((ushort4*)lo)[i] = lv;
}

// ---------------------------------------------------------------------------
// Bucket kernel (unchanged)
// ---------------------------------------------------------------------------
__global__ __launch_bounds__(256) void bucket_k(
    const float* __restrict__ qk, const float* __restrict__ rot,
    int* __restrict__ bkt)
{
    __shared__ float rs[64][32];
    const int bh = blockIdx.z, r = blockIdx.y;
    const int t = blockIdx.x * 256 + threadIdx.x;
    for (int i = threadIdx.x; i < 64 * 32; i += 256) {
        int f = i >> 5, j = i & 31;
        rs[f][j] = rot[(f * NH + r) * 32 + j];
    }
    __syncthreads();
    const int b = bh >> 3, h = bh & 7;
    const float* q = qk + ((size_t)(b * TT + t)) * DD + h * DHH;
    float qv[64];
#pragma unroll
    for (int f4 = 0; f4 < 16; f4++) {
        float4 tmp = ((const float4*)q)[f4];
        qv[f4 * 4 + 0] = tmp.x; qv[f4 * 4 + 1] = tmp.y;
        qv[f4 * 4 + 2] = tmp.z; qv[f4 * 4 + 3] = tmp.w;
    }
    float rv[32];
#pragma unroll
    for (int j = 0; j < 32; j++) rv[j] = 0.f;
    for (int f = 0; f < 64; f++) {
        float qf = qv[f];
#pragma unroll
        for (int j = 0; j < 32; j++) rv[j] = fmaf(qf, rs[f][j], rv[j]);
    }
    float best = rv[0];
    int bi = 0;
#pragma unroll
    for (int j = 1; j < 32; j++) { if (rv[j] > best) { best = rv[j]; bi = j; } }
#pragma unroll
    for (int j = 0; j < 32; j++) { float v = -rv[j]; if (v > best) { best = v; bi = 32 + j; } }
    bkt[((size_t)bh * NH + r) * TT + t] = bi;
}

// ---------------------------------------------------------------------------
// Stable counting sort by bucket per (bh, round). (unchanged)
// ---------------------------------------------------------------------------
__global__ __launch_bounds__(64) void sort_k(
    const int* __restrict__ bkt, int* __restrict__ st)
{
    __shared__ int lb[TT];
    __shared__ int cnt[64];
    const int r = blockIdx.x, bh = blockIdx.y;
    const int* src = bkt + ((size_t)bh * NH + r) * TT;
    for (int t = threadIdx.x; t < TT; t += 64) lb[t] = src[t];
    __syncthreads();
    const int b = threadIdx.x;
    int c = 0;
    for (int t = 0; t < TT; t++) c += (lb[t] == b) ? 1 : 0;
    cnt[b] = c;
    __syncthreads();
    if (threadIdx.x == 0) {
        int s = 0;
        for (int i = 0; i < 64; i++) { int v = cnt[i]; cnt[i] = s; s += v; }
    }
    __syncthreads();
    int pos = cnt[b];
    int* dst = st + (size_t)bh * (NH * TT) + (size_t)r * TT;
    for (int t = 0; t < TT; t++) {
        if (lb[t] == b) { dst[pos] = t; pos++; }
    }
}

// ---------------------------------------------------------------------------
// Attention v3: swizzled LDS, register probs + in-wave softmax, shfl-based
// PV redistribution (16 accumulators/lane -> no spills). Strip of 16 bh.
// ---------------------------------------------------------------------------
__global__ __launch_bounds__(256, 2) void attn_k(
    const float* __restrict__ qk, const float* __restrict__ vbuf,
    const int* __restrict__ st, float* __restrict__ obuf,
    float* __restrict__ lseb, int bh0)
{
    __shared__ float ks[128 * 64];
    __shared__ float vs[128 * 64];
    __shared__ float invn[128];
    __shared__ int   tks[128];

    const int c   = blockIdx.x;
    const int bhl = blockIdx.y;
    const int bh  = bh0 + bhl;
    const int b   = bh >> 3, h = bh & 7;
    const int tid = threadIdx.x;
    const int* stb = st + (size_t)bh * (NH * TT);

    if (tid < 128) {
        int cc = (tid < 64) ? c : ((c + NC - 1) & (NC - 1));
        tks[tid] = stb[cc * 64 + (tid & 63)];
    }
    __syncthreads();

    {   // stage k,v (rotate-swizzled) + inv k-norms
        const int row = tid >> 1, c0 = (tid & 1) * 32;
        const int t = tks[row];
        const float4* kg = (const float4*)(qk + ((size_t)(b * TT + t)) * DD + h * DHH + c0);
        const float4* vg = (const float4*)(vbuf + ((size_t)(b * TT + t)) * DD + h * DHH + c0);
        float4 kv[8], vv[8];
        float ss = 0.f;
#pragma unroll
        for (int q = 0; q < 8; q++) {
            kv[q] = kg[q]; vv[q] = vg[q];
            ss += kv[q].x * kv[q].x + kv[q].y * kv[q].y
                + kv[q].z * kv[q].z + kv[q].w * kv[q].w;
        }
        ss += __shfl_xor(ss, 1);
        if ((tid & 1) == 0) invn[row] = 1.0f / fmaxf(sqrtf(ss), 1e-12f);
        const int sh = ((row & 15) << 2) + ((row >> 5) << 3);
#pragma unroll
        for (int q = 0; q < 8; q++) {
            int col = (c0 + 4 * q + sh) & 63;
            *(float4*)&ks[row * 64 + col] = kv[q];
            *(float4*)&vs[row * 64 + col] = vv[q];
        }
    }
    __syncthreads();

    const int lane = tid & 63;
    const int wv   = tid >> 6;
    const int ig   = lane >> 3;
    const int pp   = lane & 7;
    const int i0   = wv * 16 + ig * 2;
    const int i1   = i0 + 1;
    const int jb   = pp * 16;
    const int rbase = (pp >> 1) << 3;
    const int shq0 = ((i0 & 15) << 2) + ((i0 >> 5) << 3);
    const int shq1 = ((i1 & 15) << 2) + ((i1 >> 5) << 3);

    // ---- dots ----
    float dt0[16], dt1[16];
#pragma unroll
    for (int q = 0; q < 16; q++) { dt0[q] = 0.f; dt1[q] = 0.f; }

#pragma unroll 4
    for (int f4 = 0; f4 < 16; f4++) {
        const float4 q0 = *(const float4*)&ks[i0 * 64 + ((4 * f4 + shq0) & 63)];
        const float4 q1 = *(const float4*)&ks[i1 * 64 + ((4 * f4 + shq1) & 63)];
#pragma unroll
        for (int jj = 0; jj < 16; jj++) {
            const int j = jb + jj;
            const float4 kv = *(const float4*)&ks[j * 64 + ((4 * (f4 + jj) + rbase) & 63)];
            dt0[jj] = fmaf(q0.x, kv.x, dt0[jj]);
            dt0[jj] = fmaf(q0.y, kv.y, dt0[jj]);
            dt0[jj] = fmaf(q0.z, kv.z, dt0[jj]);
            dt0[jj] = fmaf(q0.w, kv.w, dt0[jj]);
            dt1[jj] = fmaf(q1.x, kv.x, dt1[jj]);
            dt1[jj] = fmaf(q1.y, kv.y, dt1[jj]);
            dt1[jj] = fmaf(q1.z, kv.z, dt1[jj]);
            dt1[jj] = fmaf(q1.w, kv.w, dt1[jj]);
        }
    }

    // ---- scale, self-mask, softmax over 8-lane groups ----
    const int ti0 = tks[i0], ti1 = tks[i1];
    float m0 = -INFINITY, m1 = -INFINITY;
#pragma unroll
    for (int jj = 0; jj < 16; jj++) {
        const int j = jb + jj;
        const float sc = invn[j] * 0.125f;
        const int tkj = tks[j];
        float d0 = dt0[jj] * sc; if (ti0 == tkj) d0 = -5e4f;
        float d1 = dt1[jj] * sc; if (ti1 == tkj) d1 = -5e4f;
        dt0[jj] = d0; dt1[jj] = d1;
        m0 = fmaxf(m0, d0); m1 = fmaxf(m1, d1);
    }
    m0 = fmaxf(m0, __shfl_xor(m0, 1));
    m0 = fmaxf(m0, __shfl_xor(m0, 2));
    m0 = fmaxf(m0, __shfl_xor(m0, 4));
    m1 = fmaxf(m1, __shfl_xor(m1, 1));
    m1 = fmaxf(m1, __shfl_xor(m1, 2));
    m1 = fmaxf(m1, __shfl_xor(m1, 4));
    float s0 = 0.f, s1 = 0.f;
#pragma unroll
    for (int jj = 0; jj < 16; jj++) {
        float e0 = expf(dt0[jj] - m0); dt0[jj] = e0; s0 += e0;
        float e1 = expf(dt1[jj] - m1); dt1[jj] = e1; s1 += e1;
    }
    s0 += __shfl_xor(s0, 1); s0 += __shfl_xor(s0, 2); s0 += __shfl_xor(s0, 4);
    s1 += __shfl_xor(s1, 1); s1 += __shfl_xor(s1, 2); s1 += __shfl_xor(s1, 4);
    const float lse0 = m0 + logf(s0), lse1 = m1 + logf(s1);
    const float is0 = 1.0f / s0, is1 = 1.0f / s1;
#pragma unroll
    for (int jj = 0; jj < 16; jj++) { dt0[jj] *= is0; dt1[jj] *= is1; }

    // ---- PV via shfl redistribution: lane pp owns f in [8pp, 8pp+8) ----
    float o0[8], o1[8];
#pragma unroll
    for (int q = 0; q < 8; q++) { o0[q] = 0.f; o1[q] = 0.f; }
    const int gbase = lane & 56;
#pragma unroll
    for (int src = 0; src < 8; src++) {
        const int slane = gbase | src;
#pragma unroll
        for (int jj = 0; jj < 16; jj++) {
            const int j = src * 16 + jj;
            const float p0 = __shfl(dt0[jj], slane);
            const float p1 = __shfl(dt1[jj], slane);
            const int sh = ((j & 15) << 2) + ((j >> 5) << 3);
            const float4 va = *(const float4*)&vs[j * 64 + ((pp * 8 + sh) & 63)];
            const float4 vb4 = *(const float4*)&vs[j * 64 + ((pp * 8 + 4 + sh) & 63)];
            o0[0] = fmaf(p0, va.x, o0[0]);  o0[1] = fmaf(p0, va.y, o0[1]);
            o0[2] = fmaf(p0, va.z, o0[2]);  o0[3] = fmaf(p0, va.w, o0[3]);
            o0[4] = fmaf(p0, vb4.x, o0[4]); o0[5] = fmaf(p0, vb4.y, o0[5]);
            o0[6] = fmaf(p0, vb4.z, o0[6]); o0[7] = fmaf(p0, vb4.w, o0[7]);
            o1[0] = fmaf(p1, va.x, o1[0]);  o1[1] = fmaf(p1, va.y, o1[1]);
            o1[2] = fmaf(p1, va.z, o1[2]);  o1[3] = fmaf(p1, va.w, o1[3]);
            o1[4] = fmaf(p1, vb4.x, o1[4]); o1[5] = fmaf(p1, vb4.y, o1[5]);
            o1[6] = fmaf(p1, vb4.z, o1[6]); o1[7] = fmaf(p1, vb4.w, o1[7]);
        }
    }

    const int r = c >> 6;
    const size_t ob0 = (((size_t)bhl * NH + r) * TT + ti0) * DHH + pp * 8;
    const size_t ob1 = (((size_t)bhl * NH + r) * TT + ti1) * DHH + pp * 8;
    *(float4*)(obuf + ob0)     = make_float4(o0[0], o0[1], o0[2], o0[3]);
    *(float4*)(obuf + ob0 + 4) = make_float4(o0[4], o0[5], o0[6], o0[7]);
    *(float4*)(obuf + ob1)     = make_float4(o1[0], o1[1], o1[2], o1[3]);
    *(float4*)(obuf + ob1 + 4) = make_float4(o1[4], o1[5], o1[6], o1[7]);
    if (pp == 0) {
        lseb[((size_t)bh * NH + r) * TT + ti0] = lse0;
        lseb[((size_t)bh * NH + r) * TT + ti1] = lse1;
    }
}

// ---------------------------------------------------------------------------
// Combine rounds for a 16-bh strip; writes att as interleaved hi/lo bf16 rows:
// att row (b*T+t) layout = [hi 512][lo 512] ushorts (row stride 1024).
// ---------------------------------------------------------------------------
__global__ __launch_bounds__(256) void combine_k(
    const float* __restrict__ obuf, const float* __restrict__ lseb,
    ushort_t* __restrict__ att, int bh0)
{
    int idx = blockIdx.x * 256 + threadIdx.x;
    int d = idx & 63;
    int t = (idx >> 6) & (TT - 1);
    int bhl = idx >> 18;
    int bh = bh0 + bhl;
    float l0 = lseb[((size_t)bh * NH + 0) * TT + t];
    float l1 = lseb[((size_t)bh * NH + 1) * TT + t];
    float l2 = lseb[((size_t)bh * NH + 2) * TT + t];
    float l3 = lseb[((size_t)bh * NH + 3) * TT + t];
    float m = fmaxf(fmaxf(l0, l1), fmaxf(l2, l3));
    float e0 = expf(l0 - m), e1 = expf(l1 - m), e2 = expf(l2 - m), e3 = expf(l3 - m);
    float inv = 1.0f / (e0 + e1 + e2 + e3);
    float o0 = obuf[(((size_t)bhl * NH + 0) * TT + t) * DHH + d];
    float o1 = obuf[(((size_t)bhl * NH + 1) * TT + t) * DHH + d];
    float o2 = obuf[(((size_t)bhl * NH + 2) * TT + t) * DHH + d];
    float o3 = obuf[(((size_t)bhl * NH + 3) * TT + t) * DHH + d];
    float o = (e0 * o0 + e1 * o1 + e2 * o2 + e3 * o3) * inv;
    int b = bh >> 3, h = bh & 7;
    size_t base = (size_t)(b * TT + t) * 1024 + h * DHH + d;
    unsigned short hi = f2bf(o);
    att[base]       = hi;
    att[base + 512] = f2bf(o - bf2f(hi));
}

// ---------------------------------------------------------------------------
// LayerNorm over D=512; optional dual bf16 hi/lo output.
// ---------------------------------------------------------------------------
__global__ __launch_bounds__(64) void ln_k(
    const float* __restrict__ in, const float* __restrict__ g,
    const float* __restrict__ be, float* __restrict__ out,
    ushort_t* __restrict__ oh, ushort_t* __restrict__ ol)
{
    const int row = blockIdx.x;
    const int tid = threadIdx.x;
    const float* x = in + (size_t)row * DD;
    float4 a = *(const float4*)(x + tid * 8);
    float4 b = *(const float4*)(x + tid * 8 + 4);
    float s = a.x + a.y + a.z + a.w + b.x + b.y + b.z + b.w;
#pragma unroll
    for (int o = 32; o >= 1; o >>= 1) s += __shfl_xor(s, o, 64);
    float mean = s * (1.0f / 512.0f);
    float dx[8];
    dx[0] = a.x - mean; dx[1] = a.y - mean; dx[2] = a.z - mean; dx[3] = a.w - mean;
    dx[4] = b.x - mean; dx[5] = b.y - mean; dx[6] = b.z - mean; dx[7] = b.w - mean;
    float ss = 0.f;
#pragma unroll
    for (int q = 0; q < 8; q++) ss += dx[q] * dx[q];
#pragma unroll
    for (int o = 32; o >= 1; o >>= 1) ss += __shfl_xor(ss, o, 64);
    float var = ss * (1.0f / 512.0f);
    float inv = 1.0f / sqrtf(var + 1e-6f);
    const float* gp = g + tid * 8;
    const float* bp = be + tid * 8;
    float y[8];
#pragma unroll
    for (int q = 0; q < 8; q++) y[q] = dx[q] * inv * gp[q] + bp[q];
    float* yp = out + (size_t)row * DD + tid * 8;
    *(float4*)(yp)     = make_float4(y[0], y[1], y[2], y[3]);
    *(float4*)(yp + 4) = make_float4(y[4], y[5], y[6], y[7]);
    if (oh) {
        ushort4 hv0, hv1, lv0, lv1;
        unsigned short h;
        h = f2bf(y[0]); hv0.x = h; lv0.x = f2bf(y[0] - bf2f(h));
        h = f2bf(y[1]); hv0.y = h; lv0.y = f2bf(y[1] - bf2f(h));
        h = f2bf(y[2]); hv0.z = h; lv0.z = f2bf(y[2] - bf2f(h));
        h = f2bf(y[3]); hv0.w = h; lv0.w = f2bf(y[3] - bf2f(h));
        h = f2bf(y[4]); hv1.x = h; lv1.x = f2bf(y[4] - bf2f(h));
        h = f2bf(y[5]); hv1.y = h; lv1.y = f2bf(y[5] - bf2f(h));
        h = f2bf(y[6]); hv1.z = h; lv1.z = f2bf(y[6] - bf2f(h));
        h = f2bf(y[7]); hv1.w = h; lv1.w = f2bf(y[7] - bf2f(h));
        size_t e = (size_t)row * DD + tid * 8;
        *(ushort4*)(oh + e)     = hv0;
        *(ushort4*)(oh + e + 4) = hv1;
        *(ushort4*)(ol + e)     = lv0;
        *(ushort4*)(ol + e + 4) = lv1;
    }
}

// ---------------------------------------------------------------------------
extern "C" void kernel_launch(void* const* d_in, const int* in_sizes, int n_in,
                              void* d_out, int out_size, void* d_ws, size_t ws_size,
                              hipStream_t stream)
{
    const float* src  = (const float*)d_in[0];
    const float* rots = (const float*)d_in[1];
    const float* Wqk  = (const float*)d_in[2];
    const float* Wv   = (const float*)d_in[3];
    const float* Wout = (const float*)d_in[4];
    const float* bout = (const float*)d_in[5];
    const float* W1   = (const float*)d_in[6];
    const float* b1   = (const float*)d_in[7];
    const float* W2   = (const float*)d_in[8];
    const float* b2   = (const float*)d_in[9];
    const float* g2   = (const float*)d_in[10];
    const float* be2  = (const float*)d_in[11];
    const float* gf   = (const float*)d_in[12];
    const float* bf   = (const float*)d_in[13];
    float* out = (float*)d_out;

    // ---- workspace layout ----
    char* w = (char*)d_ws;
    const size_t SZ_X = (size_t)MROWS * DD * 4;               // 33.55 MB
    float*    x     = (float*)(w);                            // R1
    ushort_t* xhl   = (ushort_t*)(w + SZ_X);                  // R2: hi | lo (8.39M elems each)
    float*    qkb   = (float*)(w + 2 * SZ_X);                 // R3: qk fp32 / att hi|lo interleaved
    ushort_t* attb  = (ushort_t*)(w + 2 * SZ_X);
    float*    vb    = (float*)(w + 3 * SZ_X);                 // R4: v / yff
    float*    obuf  = (float*)(w + 4 * SZ_X);                 // R5: obuf strip / h1 strip (67.1 MB)
    ushort_t* h1b   = (ushort_t*)(w + 4 * SZ_X);
    ushort_t* wb    = (ushort_t*)(w + 6 * SZ_X);              // weights hi/lo staging (10.5 MB)
    char*     tail  = w + 6 * SZ_X + 5242880 * 2;
    int*      bkt   = (int*)(tail);
    int*      st    = (int*)(tail + (size_t)BHH * NH * TT * 4);
    float*    lseb  = (float*)(tail + 2 * (size_t)BHH * NH * TT * 4);

    const size_t XHALF = (size_t)MROWS * DD;                  // 8,388,608 elems
    ushort_t* xh = xhl;            ushort_t* xl = xhl + XHALF;
    ushort_t* wvh = wb;            ushort_t* wvl = wb + 262144;
    ushort_t* woh = wb + 524288;   ushort_t* wol = wb + 786432;
    ushort_t* w1h = wb + 1048576;  ushort_t* w1l = wb + 2097152;
    ushort_t* w2h = wb + 3145728;  ushort_t* w2l = wb + 4194304;
    const size_t H1HALF = (size_t)8192 * DFFN;                // 16,777,216 elems
    ushort_t* h1h = h1b;           ushort_t* h1l = h1b + H1HALF;

    hipMemcpyAsync(x, src, SZ_X, hipMemcpyDeviceToDevice, stream);
    cvt_k<<<(MROWS * DD / 4 + 255) / 256, 256, 0, stream>>>(src, xh, xl, MROWS * DD / 4);

    for (int i = 0; i < LLAY; i++) {
        const float* Wqk_i = Wqk + (size_t)i * DD * DD;
        const float* Wv_i  = Wv  + (size_t)i * DD * DD;
        const float* Wout_i= Wout+ (size_t)i * DD * DD;
        const float* bout_i= bout+ (size_t)i * DD;
        const float* W1_i  = W1  + (size_t)i * DFFN * DD;
        const float* b1_i  = b1  + (size_t)i * DFFN;
        const float* W2_i  = W2  + (size_t)i * DD * DFFN;
        const float* b2_i  = b2  + (size_t)i * DD;
        const float* g2_i  = g2  + (size_t)i * DD;
        const float* be2_i = be2 + (size_t)i * DD;
        const float* rot_i = rots + (size_t)i * DHH * NH * 32;

        // stage this layer's weights as bf16 hi/lo
        cvt_k<<<(262144 / 4 + 255) / 256, 256, 0, stream>>>(Wv_i, wvh, wvl, 262144 / 4);
        cvt_k<<<(262144 / 4 + 255) / 256, 256, 0, stream>>>(Wout_i, woh, wol, 262144 / 4);
        cvt_k<<<(1048576 / 4 + 255) / 256, 256, 0, stream>>>(W1_i, w1h, w1l, 1048576 / 4);
        cvt_k<<<(1048576 / 4 + 255) / 256, 256, 0, stream>>>(W2_i, w2h, w2l, 1048576 / 4);

        // qk = x @ Wqk^T  (fp32: feeds LSH argmax)
        gemm_k<<<dim3(4, 128), 256, 0, stream>>>(x, Wqk_i, nullptr, nullptr, qkb,
                                                 MROWS, DD, DD, 0);
        // v = x @ Wv^T  (bf16x3)
        gemm_bf3_k<<<dim3(4, 128), 256, 0, stream>>>(xh, xl, DD, wvh, wvl,
                                                     nullptr, nullptr, vb, nullptr, nullptr,
                                                     MROWS, DD, DD, 0);
        bucket_k<<<dim3(16, NH, BHH), 256, 0, stream>>>(qkb, rot_i, bkt);
        sort_k<<<dim3(NH, BHH), 64, 0, stream>>>(bkt, st);

        // attention in 2 strips of 16 bh (obuf reused); combine -> att hi/lo
        for (int s = 0; s < 2; s++) {
            attn_k<<<dim3(NC, 16), 256, 0, stream>>>(qkb, vb, st, obuf, lseb, s * 16);
            combine_k<<<16384, 256, 0, stream>>>(obuf, lseb, attb, s * 16);
        }

        // x = x + att @ Wout^T + bout ; also emit x2 as hi/lo (-> R2)
        gemm_bf3_k<<<dim3(4, 128), 256, 0, stream>>>(attb, attb + 512, 1024, woh, wol,
                                                     bout_i, x, x, xh, xl,
                                                     MROWS, DD, DD, 0);
        // FFN in 2 strips of 8192 rows (h1 hi/lo reuses obuf region)
        for (int s = 0; s < 2; s++) {
            const size_t ro = (size_t)s * 8192;
            gemm_bf3_k<<<dim3(16, 64), 256, 0, stream>>>(xh + ro * DD, xl + ro * DD, DD,
                                                         w1h, w1l, b1_i, nullptr,
                                                         nullptr, h1h, h1l,
                                                         8192, DFFN, DD, 1);
            gemm_bf3_k<<<dim3(4, 64), 256, 0, stream>>>(h1h, h1l, DFFN, w2h, w2l,
                                                        b2_i, x + ro * DD,
                                                        vb + ro * DD, nullptr, nullptr,
                                                        8192, DD, DFFN, 0);
        }
        // x = LN(yff); also emit hi/lo for next layer
        ln_k<<<MROWS, 64, 0, stream>>>(vb, g2_i, be2_i, x, xh, xl);
    }
    ln_k<<<MROWS, 64, 0, stream>>>(x, gf, bf, out, nullptr, nullptr);
}

// Round 4
// 3745.102 us; speedup vs baseline: 3.3440x; 1.5535x over previous
//
#include <hip/hip_runtime.h>
#include <math.h>

#define TT    4096
#define DD    512
#define HH    8
#define DHH   64
#define NH    4
#define LLAY  4
#define DFFN  2048
#define BHH   32          // B*H
#define NC    256         // chunks per bh (NH*NB)
#define MROWS 16384       // B*T

typedef __attribute__((ext_vector_type(8))) short s16x8;
typedef __attribute__((ext_vector_type(4))) float f32x4;
typedef unsigned short ushort_t;

union U4 { unsigned u[4]; s16x8 v; };

__device__ __forceinline__ unsigned short f2bf(float f) {
    unsigned u = __float_as_uint(f);
    unsigned r = (u + 0x7FFFu + ((u >> 16) & 1u)) >> 16;
    return (unsigned short)r;
}
__device__ __forceinline__ float bf2f(unsigned short h) {
    return __uint_as_float(((unsigned)h) << 16);
}

// ---------------------------------------------------------------------------
// fp32 GEMM (qk = x @ Wqk^T only: argmax-critical path)
// ---------------------------------------------------------------------------
__global__ __launch_bounds__(256) void gemm_k(
    const float* __restrict__ A, const float* __restrict__ W,
    const float* __restrict__ bias, const float* __restrict__ resid,
    float* __restrict__ C, int M, int N, int K, int relu)
{
    __shared__ float As[16][128];
    __shared__ float Ws[16][128];
    const int tid = threadIdx.x;
    const int tx = tid & 15, ty = tid >> 4;
    const int row0 = blockIdx.y * 128, col0 = blockIdx.x * 128;
    const int lrow = tid >> 1, lk = (tid & 1) * 8;

    float acc[8][8];
#pragma unroll
    for (int i = 0; i < 8; i++)
#pragma unroll
        for (int j = 0; j < 8; j++) acc[i][j] = 0.f;

    const float* Ap = A + (size_t)(row0 + lrow) * K + lk;
    const float* Wp = W + (size_t)(col0 + lrow) * K + lk;

    for (int k0 = 0; k0 < K; k0 += 16) {
        float4 a0 = *(const float4*)(Ap + k0);
        float4 a1 = *(const float4*)(Ap + k0 + 4);
        float4 w0 = *(const float4*)(Wp + k0);
        float4 w1 = *(const float4*)(Wp + k0 + 4);
        __syncthreads();
        As[lk + 0][lrow] = a0.x; As[lk + 1][lrow] = a0.y;
        As[lk + 2][lrow] = a0.z; As[lk + 3][lrow] = a0.w;
        As[lk + 4][lrow] = a1.x; As[lk + 5][lrow] = a1.y;
        As[lk + 6][lrow] = a1.z; As[lk + 7][lrow] = a1.w;
        Ws[lk + 0][lrow] = w0.x; Ws[lk + 1][lrow] = w0.y;
        Ws[lk + 2][lrow] = w0.z; Ws[lk + 3][lrow] = w0.w;
        Ws[lk + 4][lrow] = w1.x; Ws[lk + 5][lrow] = w1.y;
        Ws[lk + 6][lrow] = w1.z; Ws[lk + 7][lrow] = w1.w;
        __syncthreads();
#pragma unroll
        for (int kk = 0; kk < 16; kk++) {
            float a[8], bb[8];
#pragma unroll
            for (int i = 0; i < 8; i++) a[i] = As[kk][ty * 8 + i];
#pragma unroll
            for (int j = 0; j < 8; j++) bb[j] = Ws[kk][tx * 8 + j];
#pragma unroll
            for (int i = 0; i < 8; i++)
#pragma unroll
                for (int j = 0; j < 8; j++)
                    acc[i][j] = fmaf(a[i], bb[j], acc[i][j]);
        }
    }

#pragma unroll
    for (int i = 0; i < 8; i++) {
        int row = row0 + ty * 8 + i;
#pragma unroll
        for (int j = 0; j < 8; j++) {
            int col = col0 + tx * 8 + j;
            float v = acc[i][j];
            if (bias) v += bias[col];
            if (relu) v = fmaxf(v, 0.f);
            if (resid) v += resid[(size_t)row * N + col];
            C[(size_t)row * N + col] = v;
        }
    }
}

// ---------------------------------------------------------------------------
// bf16x3 MFMA GEMM (unchanged from R3, verified)
// ---------------------------------------------------------------------------
__global__ __launch_bounds__(256) void gemm_bf3_k(
    const ushort_t* __restrict__ Ah, const ushort_t* __restrict__ Al, int lda,
    const ushort_t* __restrict__ Wh, const ushort_t* __restrict__ Wl,
    const float* __restrict__ bias, const float* __restrict__ resid,
    float* __restrict__ outf, ushort_t* __restrict__ outh, ushort_t* __restrict__ outl,
    int M, int N, int K, int relu)
{
    __shared__ __align__(16) ushort_t lds[4 * 128 * 32];   // Ah,Al,Wh,Wl
    const int tid  = threadIdx.x;
    const int lane = tid & 63;
    const int wv   = tid >> 6;
    const int wm   = wv >> 1, wn = wv & 1;
    const int row0 = blockIdx.y * 128, col0 = blockIdx.x * 128;
    const int g    = lane >> 4;

    f32x4 acc[4][4];
#pragma unroll
    for (int mi = 0; mi < 4; mi++)
#pragma unroll
        for (int ni = 0; ni < 4; ni++) acc[mi][ni] = (f32x4)(0.f);

    const int srow0 = wv * 32;

    for (int k0 = 0; k0 < K; k0 += 32) {
        __syncthreads();
#pragma unroll
        for (int ii = 0; ii < 2; ii++) {
            const int r   = srow0 + ii * 16 + (lane >> 2);
            const int ug  = (((lane & 3) ^ ((r >> 1) & 3)) << 3);
            const size_t ga = (size_t)(row0 + r) * lda + k0 + ug;
            const size_t gw = (size_t)(col0 + r) * K   + k0 + ug;
            const int lo  = (srow0 + ii * 16) * 32;
            __builtin_amdgcn_global_load_lds(
                (const __attribute__((address_space(1))) void*)(Ah + ga),
                (__attribute__((address_space(3))) void*)&lds[0 * 4096 + lo], 16, 0, 0);
            __builtin_amdgcn_global_load_lds(
                (const __attribute__((address_space(1))) void*)(Al + ga),
                (__attribute__((address_space(3))) void*)&lds[1 * 4096 + lo], 16, 0, 0);
            __builtin_amdgcn_global_load_lds(
                (const __attribute__((address_space(1))) void*)(Wh + gw),
                (__attribute__((address_space(3))) void*)&lds[2 * 4096 + lo], 16, 0, 0);
            __builtin_amdgcn_global_load_lds(
                (const __attribute__((address_space(1))) void*)(Wl + gw),
                (__attribute__((address_space(3))) void*)&lds[3 * 4096 + lo], 16, 0, 0);
        }
        __syncthreads();

        s16x8 ah[4], al[4], wh[4], wl[4];
#pragma unroll
        for (int mi = 0; mi < 4; mi++) {
            const int m  = wm * 64 + mi * 16 + (lane & 15);
            const int pu = ((g ^ ((m >> 1) & 3)) << 3);
            ah[mi] = *(const s16x8*)&lds[0 * 4096 + m * 32 + pu];
            al[mi] = *(const s16x8*)&lds[1 * 4096 + m * 32 + pu];
            const int n  = wn * 64 + mi * 16 + (lane & 15);
            const int pn = ((g ^ ((n >> 1) & 3)) << 3);
            wh[mi] = *(const s16x8*)&lds[2 * 4096 + n * 32 + pn];
            wl[mi] = *(const s16x8*)&lds[3 * 4096 + n * 32 + pn];
        }
#pragma unroll
        for (int mi = 0; mi < 4; mi++)
#pragma unroll
            for (int ni = 0; ni < 4; ni++) {
                acc[mi][ni] = __builtin_amdgcn_mfma_f32_16x16x32_bf16(ah[mi], wh[ni], acc[mi][ni], 0, 0, 0);
                acc[mi][ni] = __builtin_amdgcn_mfma_f32_16x16x32_bf16(al[mi], wh[ni], acc[mi][ni], 0, 0, 0);
                acc[mi][ni] = __builtin_amdgcn_mfma_f32_16x16x32_bf16(ah[mi], wl[ni], acc[mi][ni], 0, 0, 0);
            }
    }

#pragma unroll
    for (int mi = 0; mi < 4; mi++) {
#pragma unroll
        for (int ni = 0; ni < 4; ni++) {
#pragma unroll
            for (int r = 0; r < 4; r++) {
                const int row = row0 + wm * 64 + mi * 16 + g * 4 + r;
                const int col = col0 + wn * 64 + ni * 16 + (lane & 15);
                float v = acc[mi][ni][r];
                if (bias)  v += bias[col];
                if (relu)  v = fmaxf(v, 0.f);
                if (resid) v += resid[(size_t)row * N + col];
                if (outf)  outf[(size_t)row * N + col] = v;
                if (outh) {
                    unsigned short h = f2bf(v);
                    outh[(size_t)row * N + col] = h;
                    outl[(size_t)row * N + col] = f2bf(v - bf2f(h));
                }
            }
        }
    }
}

// ---------------------------------------------------------------------------
// fp32 -> bf16 hi/lo converter
// ---------------------------------------------------------------------------
__global__ __launch_bounds__(256) void cvt_k(
    const float* __restrict__ in, ushort_t* __restrict__ hi,
    ushort_t* __restrict__ lo, int n4)
{
    int i = blockIdx.x * 256 + threadIdx.x;
    if (i >= n4) return;
    float4 v = ((const float4*)in)[i];
    unsigned short h0 = f2bf(v.x), h1 = f2bf(v.y), h2 = f2bf(v.z), h3 = f2bf(v.w);
    ushort4 hv; hv.x = h0; hv.y = h1; hv.z = h2; hv.w = h3;
    ushort4 lv;
    lv.x = f2bf(v.x - bf2f(h0)); lv.y = f2bf(v.y - bf2f(h1));
    lv.z = f2bf(v.z - bf2f(h2)); lv.w = f2bf(v.w - bf2f(h3));
    ((ushort4*)hi)[i] = hv;
    ((ushort4*)lo)[i] = lv;
}

// ---------------------------------------------------------------------------
// Bucket kernel (unchanged)
// ---------------------------------------------------------------------------
__global__ __launch_bounds__(256) void bucket_k(
    const float* __restrict__ qk, const float* __restrict__ rot,
    int* __restrict__ bkt)
{
    __shared__ float rs[64][32];
    const int bh = blockIdx.z, r = blockIdx.y;
    const int t = blockIdx.x * 256 + threadIdx.x;
    for (int i = threadIdx.x; i < 64 * 32; i += 256) {
        int f = i >> 5, j = i & 31;
        rs[f][j] = rot[(f * NH + r) * 32 + j];
    }
    __syncthreads();
    const int b = bh >> 3, h = bh & 7;
    const float* q = qk + ((size_t)(b * TT + t)) * DD + h * DHH;
    float qv[64];
#pragma unroll
    for (int f4 = 0; f4 < 16; f4++) {
        float4 tmp = ((const float4*)q)[f4];
        qv[f4 * 4 + 0] = tmp.x; qv[f4 * 4 + 1] = tmp.y;
        qv[f4 * 4 + 2] = tmp.z; qv[f4 * 4 + 3] = tmp.w;
    }
    float rv[32];
#pragma unroll
    for (int j = 0; j < 32; j++) rv[j] = 0.f;
    for (int f = 0; f < 64; f++) {
        float qf = qv[f];
#pragma unroll
        for (int j = 0; j < 32; j++) rv[j] = fmaf(qf, rs[f][j], rv[j]);
    }
    float best = rv[0];
    int bi = 0;
#pragma unroll
    for (int j = 1; j < 32; j++) { if (rv[j] > best) { best = rv[j]; bi = j; } }
#pragma unroll
    for (int j = 0; j < 32; j++) { float v = -rv[j]; if (v > best) { best = v; bi = 32 + j; } }
    bkt[((size_t)bh * NH + r) * TT + t] = bi;
}

// ---------------------------------------------------------------------------
// Parallel stable counting sort per (bh, round). 256 threads.
// 128 segments x 32 items; per-segment histograms; stable scatter.
// ---------------------------------------------------------------------------
__global__ __launch_bounds__(256) void sort_k(
    const int* __restrict__ bkt, int* __restrict__ st)
{
    __shared__ int lb[TT];
    __shared__ unsigned short cnt[128][64];
    __shared__ int base[64];
    const int r = blockIdx.x, bh = blockIdx.y;
    const int tid = threadIdx.x;
    const int* src = bkt + ((size_t)bh * NH + r) * TT;

    const int4* s4 = (const int4*)src;
    int4* l4 = (int4*)lb;
#pragma unroll
    for (int q = 0; q < 4; q++) l4[tid + q * 256] = s4[tid + q * 256];
    unsigned* cz = (unsigned*)cnt;
#pragma unroll
    for (int q = 0; q < 16; q++) cz[tid + q * 256] = 0;
    __syncthreads();

    if (tid < 128) {
        for (int it = 0; it < 32; it++) {
            int bb = lb[tid * 32 + it];
            cnt[tid][bb]++;
        }
    }
    __syncthreads();

    if (tid < 64) {
        const int bb = tid;
        int run = 0;
        for (int s = 0; s < 128; s++) {
            int t = cnt[s][bb];
            cnt[s][bb] = (unsigned short)run;
            run += t;
        }
        int inc = run;
#pragma unroll
        for (int off = 1; off < 64; off <<= 1) {
            int n = __shfl_up(inc, off, 64);
            if (tid >= off) inc += n;
        }
        base[bb] = inc - run;
    }
    __syncthreads();

    if (tid < 128) {
        int* dst = st + (size_t)bh * (NH * TT) + (size_t)r * TT;
        for (int it = 0; it < 32; it++) {
            int t = tid * 32 + it;
            int bb = lb[t];
            int pos = base[bb] + (int)cnt[tid][bb];
            cnt[tid][bb]++;
            dst[pos] = t;
        }
    }
}

// ---------------------------------------------------------------------------
// Attention v4: MFMA. S^T = mfma(K, Q) (swapped -> lane-local softmax),
// PV via K=32 MFMA with shfl repack of P^T regs into A-frag layout.
// Q,K,P,V all hi/lo bf16 (3-term) -> ~2^-18 accuracy. LDS ~72KB, 2 blk/CU.
// ---------------------------------------------------------------------------
__global__ __launch_bounds__(256, 2) void attn_k(
    const float* __restrict__ qk, const float* __restrict__ vbuf,
    const int* __restrict__ st, float* __restrict__ obuf,
    float* __restrict__ lseb, int bh0)
{
    __shared__ __align__(16) ushort_t ksh[128 * 72];   // K hi (rows pad 72)
    __shared__ __align__(16) ushort_t ksl[128 * 72];   // K lo
    __shared__ __align__(16) unsigned vsp[128 * 66];   // V packed hi|lo<<16 (pad 66)
    __shared__ float invn[128];
    __shared__ int   tks[128];

    const int c   = blockIdx.x;
    const int bhl = blockIdx.y;
    const int bh  = bh0 + bhl;
    const int b   = bh >> 3, h = bh & 7;
    const int tid = threadIdx.x;
    const int* stb = st + (size_t)bh * (NH * TT);

    if (tid < 128) {
        int cc = (tid < 64) ? c : ((c + NC - 1) & (NC - 1));
        tks[tid] = stb[cc * 64 + (tid & 63)];
    }
    __syncthreads();

    {   // stage K hi/lo + V packed + inv k-norms (2 threads per row)
        const int row = tid >> 1, c0 = (tid & 1) * 32;
        const int t = tks[row];
        const float4* kg = (const float4*)(qk + ((size_t)(b * TT + t)) * DD + h * DHH + c0);
        const float4* vg = (const float4*)(vbuf + ((size_t)(b * TT + t)) * DD + h * DHH + c0);
        float kv[32], vv[32];
        float ss = 0.f;
#pragma unroll
        for (int q = 0; q < 8; q++) {
            float4 kq = kg[q], vq = vg[q];
            kv[4 * q + 0] = kq.x; kv[4 * q + 1] = kq.y; kv[4 * q + 2] = kq.z; kv[4 * q + 3] = kq.w;
            vv[4 * q + 0] = vq.x; vv[4 * q + 1] = vq.y; vv[4 * q + 2] = vq.z; vv[4 * q + 3] = vq.w;
            ss += kq.x * kq.x + kq.y * kq.y + kq.z * kq.z + kq.w * kq.w;
        }
        ss += __shfl_xor(ss, 1);
        if ((tid & 1) == 0) invn[row] = 1.0f / fmaxf(sqrtf(ss), 1e-12f);

        unsigned hw[16], lw[16];
#pragma unroll
        for (int e = 0; e < 16; e++) {
            float a = kv[2 * e], b2 = kv[2 * e + 1];
            unsigned short ha = f2bf(a), hb = f2bf(b2);
            hw[e] = (unsigned)ha | ((unsigned)hb << 16);
            lw[e] = (unsigned)f2bf(a - bf2f(ha)) | ((unsigned)f2bf(b2 - bf2f(hb)) << 16);
        }
        uint4* kdh = (uint4*)&ksh[row * 72 + c0];
        uint4* kdl = (uint4*)&ksl[row * 72 + c0];
#pragma unroll
        for (int q = 0; q < 4; q++) {
            kdh[q] = make_uint4(hw[4 * q], hw[4 * q + 1], hw[4 * q + 2], hw[4 * q + 3]);
            kdl[q] = make_uint4(lw[4 * q], lw[4 * q + 1], lw[4 * q + 2], lw[4 * q + 3]);
        }
        unsigned pw[32];
#pragma unroll
        for (int e = 0; e < 32; e++) {
            unsigned short hv = f2bf(vv[e]);
            pw[e] = (unsigned)hv | ((unsigned)f2bf(vv[e] - bf2f(hv)) << 16);
        }
        uint2* vd = (uint2*)&vsp[row * 66 + c0];
#pragma unroll
        for (int q = 0; q < 16; q++) vd[q] = make_uint2(pw[2 * q], pw[2 * q + 1]);
    }
    __syncthreads();

    const int lane = tid & 63;
    const int wv   = tid >> 6;
    const int cc16 = lane & 15;
    const int g    = lane >> 4;
    const int rr   = c >> 6;

    // ---- S^T: 8 j-tiles x (this wave's i-tile), K=64 over 2 ksteps, 3-term ----
    f32x4 stt[8];
#pragma unroll
    for (int jt = 0; jt < 8; jt++) stt[jt] = (f32x4)(0.f);

    const int qrow = wv * 16 + cc16;
#pragma unroll
    for (int ks = 0; ks < 2; ks++) {
        s16x8 qh = *(const s16x8*)&ksh[qrow * 72 + ks * 32 + g * 8];
        s16x8 ql = *(const s16x8*)&ksl[qrow * 72 + ks * 32 + g * 8];
#pragma unroll
        for (int jt = 0; jt < 8; jt++) {
            const int krow = jt * 16 + cc16;
            s16x8 ah = *(const s16x8*)&ksh[krow * 72 + ks * 32 + g * 8];
            s16x8 al = *(const s16x8*)&ksl[krow * 72 + ks * 32 + g * 8];
            stt[jt] = __builtin_amdgcn_mfma_f32_16x16x32_bf16(ah, qh, stt[jt], 0, 0, 0);
            stt[jt] = __builtin_amdgcn_mfma_f32_16x16x32_bf16(al, qh, stt[jt], 0, 0, 0);
            stt[jt] = __builtin_amdgcn_mfma_f32_16x16x32_bf16(ah, ql, stt[jt], 0, 0, 0);
        }
    }

    // ---- scale, mask, softmax (lane-local over 32 + shfl_xor 16/32) ----
    const int tqi = tks[wv * 16 + cc16];
    float m = -INFINITY;
#pragma unroll
    for (int jt = 0; jt < 8; jt++) {
#pragma unroll
        for (int r4 = 0; r4 < 4; r4++) {
            const int j = jt * 16 + g * 4 + r4;
            float d = stt[jt][r4] * invn[j] * 0.125f;
            if (tqi == tks[j]) d = -5e4f;
            stt[jt][r4] = d;
            m = fmaxf(m, d);
        }
    }
    m = fmaxf(m, __shfl_xor(m, 16));
    m = fmaxf(m, __shfl_xor(m, 32));
    float s = 0.f;
#pragma unroll
    for (int jt = 0; jt < 8; jt++) {
#pragma unroll
        for (int r4 = 0; r4 < 4; r4++) {
            float e = expf(stt[jt][r4] - m);
            stt[jt][r4] = e;
            s += e;
        }
    }
    s += __shfl_xor(s, 16);
    s += __shfl_xor(s, 32);
    const float is = 1.0f / s;
    if (g == 0) lseb[((size_t)bh * NH + rr) * TT + tqi] = m + logf(s);

    // ---- pack probs hi/lo as u32 pairs (r0r1),(r2r3) per j-tile ----
    unsigned ph[8][2], pl[8][2];
#pragma unroll
    for (int jt = 0; jt < 8; jt++) {
#pragma unroll
        for (int w2 = 0; w2 < 2; w2++) {
            float p0 = stt[jt][2 * w2] * is;
            float p1 = stt[jt][2 * w2 + 1] * is;
            unsigned short h0 = f2bf(p0), h1 = f2bf(p1);
            ph[jt][w2] = (unsigned)h0 | ((unsigned)h1 << 16);
            pl[jt][w2] = (unsigned)f2bf(p0 - bf2f(h0)) | ((unsigned)f2bf(p1 - bf2f(h1)) << 16);
        }
    }

    // ---- PV: O = P * V, 4 ksteps of K=32, hi/lo 3-term ----
    f32x4 occ[4];
#pragma unroll
    for (int nt = 0; nt < 4; nt++) occ[nt] = (f32x4)(0.f);

    const int srcLow  = ((g & 1) << 5) + cc16;   // lane of g'=(g&1)*2
    const int srcHigh = srcLow + 16;
    const bool hiT = (lane & 32) != 0;           // g>=2 -> t = 2ks+1

#pragma unroll
    for (int ks = 0; ks < 4; ks++) {
        U4 Phi, Plo;
        {
            unsigned a0 = (unsigned)__shfl((int)ph[2 * ks][0], srcLow);
            unsigned a1 = (unsigned)__shfl((int)ph[2 * ks][1], srcLow);
            unsigned a2 = (unsigned)__shfl((int)ph[2 * ks][0], srcHigh);
            unsigned a3 = (unsigned)__shfl((int)ph[2 * ks][1], srcHigh);
            unsigned b0 = (unsigned)__shfl((int)ph[2 * ks + 1][0], srcLow);
            unsigned b1 = (unsigned)__shfl((int)ph[2 * ks + 1][1], srcLow);
            unsigned b2 = (unsigned)__shfl((int)ph[2 * ks + 1][0], srcHigh);
            unsigned b3 = (unsigned)__shfl((int)ph[2 * ks + 1][1], srcHigh);
            Phi.u[0] = hiT ? b0 : a0; Phi.u[1] = hiT ? b1 : a1;
            Phi.u[2] = hiT ? b2 : a2; Phi.u[3] = hiT ? b3 : a3;
            unsigned c0 = (unsigned)__shfl((int)pl[2 * ks][0], srcLow);
            unsigned c1 = (unsigned)__shfl((int)pl[2 * ks][1], srcLow);
            unsigned c2 = (unsigned)__shfl((int)pl[2 * ks][0], srcHigh);
            unsigned c3 = (unsigned)__shfl((int)pl[2 * ks][1], srcHigh);
            unsigned d0 = (unsigned)__shfl((int)pl[2 * ks + 1][0], srcLow);
            unsigned d1 = (unsigned)__shfl((int)pl[2 * ks + 1][1], srcLow);
            unsigned d2 = (unsigned)__shfl((int)pl[2 * ks + 1][0], srcHigh);
            unsigned d3 = (unsigned)__shfl((int)pl[2 * ks + 1][1], srcHigh);
            Plo.u[0] = hiT ? d0 : c0; Plo.u[1] = hiT ? d1 : c1;
            Plo.u[2] = hiT ? d2 : c2; Plo.u[3] = hiT ? d3 : c3;
        }
#pragma unroll
        for (int nt = 0; nt < 4; nt++) {
            unsigned u[8];
#pragma unroll
            for (int e = 0; e < 8; e++)
                u[e] = vsp[(32 * ks + 8 * g + e) * 66 + nt * 16 + cc16];
            U4 Vh, Vl;
#pragma unroll
            for (int m2 = 0; m2 < 4; m2++) {
                Vh.u[m2] = (u[2 * m2] & 0xffffu) | (u[2 * m2 + 1] << 16);
                Vl.u[m2] = (u[2 * m2] >> 16) | (u[2 * m2 + 1] & 0xffff0000u);
            }
            occ[nt] = __builtin_amdgcn_mfma_f32_16x16x32_bf16(Phi.v, Vh.v, occ[nt], 0, 0, 0);
            occ[nt] = __builtin_amdgcn_mfma_f32_16x16x32_bf16(Plo.v, Vh.v, occ[nt], 0, 0, 0);
            occ[nt] = __builtin_amdgcn_mfma_f32_16x16x32_bf16(Phi.v, Vl.v, occ[nt], 0, 0, 0);
        }
    }

    // ---- write O: lane holds O[i = wv*16 + 4g + r][d = 16nt + cc16] ----
#pragma unroll
    for (int r4 = 0; r4 < 4; r4++) {
        const int i = wv * 16 + g * 4 + r4;
        const int ti = tks[i];
        float* dst = obuf + (((size_t)bhl * NH + rr) * TT + ti) * DHH + cc16;
        dst[0]  = occ[0][r4];
        dst[16] = occ[1][r4];
        dst[32] = occ[2][r4];
        dst[48] = occ[3][r4];
    }
}

// ---------------------------------------------------------------------------
// Combine rounds (unchanged from R3)
// ---------------------------------------------------------------------------
__global__ __launch_bounds__(256) void combine_k(
    const float* __restrict__ obuf, const float* __restrict__ lseb,
    ushort_t* __restrict__ att, int bh0)
{
    int idx = blockIdx.x * 256 + threadIdx.x;
    int d = idx & 63;
    int t = (idx >> 6) & (TT - 1);
    int bhl = idx >> 18;
    int bh = bh0 + bhl;
    float l0 = lseb[((size_t)bh * NH + 0) * TT + t];
    float l1 = lseb[((size_t)bh * NH + 1) * TT + t];
    float l2 = lseb[((size_t)bh * NH + 2) * TT + t];
    float l3 = lseb[((size_t)bh * NH + 3) * TT + t];
    float m = fmaxf(fmaxf(l0, l1), fmaxf(l2, l3));
    float e0 = expf(l0 - m), e1 = expf(l1 - m), e2 = expf(l2 - m), e3 = expf(l3 - m);
    float inv = 1.0f / (e0 + e1 + e2 + e3);
    float o0 = obuf[(((size_t)bhl * NH + 0) * TT + t) * DHH + d];
    float o1 = obuf[(((size_t)bhl * NH + 1) * TT + t) * DHH + d];
    float o2 = obuf[(((size_t)bhl * NH + 2) * TT + t) * DHH + d];
    float o3 = obuf[(((size_t)bhl * NH + 3) * TT + t) * DHH + d];
    float o = (e0 * o0 + e1 * o1 + e2 * o2 + e3 * o3) * inv;
    int b = bh >> 3, h = bh & 7;
    size_t base = (size_t)(b * TT + t) * 1024 + h * DHH + d;
    unsigned short hi = f2bf(o);
    att[base]       = hi;
    att[base + 512] = f2bf(o - bf2f(hi));
}

// ---------------------------------------------------------------------------
// LayerNorm over D=512; optional dual bf16 hi/lo output (unchanged)
// ---------------------------------------------------------------------------
__global__ __launch_bounds__(64) void ln_k(
    const float* __restrict__ in, const float* __restrict__ g,
    const float* __restrict__ be, float* __restrict__ out,
    ushort_t* __restrict__ oh, ushort_t* __restrict__ ol)
{
    const int row = blockIdx.x;
    const int tid = threadIdx.x;
    const float* x = in + (size_t)row * DD;
    float4 a = *(const float4*)(x + tid * 8);
    float4 b = *(const float4*)(x + tid * 8 + 4);
    float s = a.x + a.y + a.z + a.w + b.x + b.y + b.z + b.w;
#pragma unroll
    for (int o = 32; o >= 1; o >>= 1) s += __shfl_xor(s, o, 64);
    float mean = s * (1.0f / 512.0f);
    float dx[8];
    dx[0] = a.x - mean; dx[1] = a.y - mean; dx[2] = a.z - mean; dx[3] = a.w - mean;
    dx[4] = b.x - mean; dx[5] = b.y - mean; dx[6] = b.z - mean; dx[7] = b.w - mean;
    float ss = 0.f;
#pragma unroll
    for (int q = 0; q < 8; q++) ss += dx[q] * dx[q];
#pragma unroll
    for (int o = 32; o >= 1; o >>= 1) ss += __shfl_xor(ss, o, 64);
    float var = ss * (1.0f / 512.0f);
    float inv = 1.0f / sqrtf(var + 1e-6f);
    const float* gp = g + tid * 8;
    const float* bp = be + tid * 8;
    float y[8];
#pragma unroll
    for (int q = 0; q < 8; q++) y[q] = dx[q] * inv * gp[q] + bp[q];
    float* yp = out + (size_t)row * DD + tid * 8;
    *(float4*)(yp)     = make_float4(y[0], y[1], y[2], y[3]);
    *(float4*)(yp + 4) = make_float4(y[4], y[5], y[6], y[7]);
    if (oh) {
        ushort4 hv0, hv1, lv0, lv1;
        unsigned short h;
        h = f2bf(y[0]); hv0.x = h; lv0.x = f2bf(y[0] - bf2f(h));
        h = f2bf(y[1]); hv0.y = h; lv0.y = f2bf(y[1] - bf2f(h));
        h = f2bf(y[2]); hv0.z = h; lv0.z = f2bf(y[2] - bf2f(h));
        h = f2bf(y[3]); hv0.w = h; lv0.w = f2bf(y[3] - bf2f(h));
        h = f2bf(y[4]); hv1.x = h; lv1.x = f2bf(y[4] - bf2f(h));
        h = f2bf(y[5]); hv1.y = h; lv1.y = f2bf(y[5] - bf2f(h));
        h = f2bf(y[6]); hv1.z = h; lv1.z = f2bf(y[6] - bf2f(h));
        h = f2bf(y[7]); hv1.w = h; lv1.w = f2bf(y[7] - bf2f(h));
        size_t e = (size_t)row * DD + tid * 8;
        *(ushort4*)(oh + e)     = hv0;
        *(ushort4*)(oh + e + 4) = hv1;
        *(ushort4*)(ol + e)     = lv0;
        *(ushort4*)(ol + e + 4) = lv1;
    }
}

// ---------------------------------------------------------------------------
extern "C" void kernel_launch(void* const* d_in, const int* in_sizes, int n_in,
                              void* d_out, int out_size, void* d_ws, size_t ws_size,
                              hipStream_t stream)
{
    const float* src  = (const float*)d_in[0];
    const float* rots = (const float*)d_in[1];
    const float* Wqk  = (const float*)d_in[2];
    const float* Wv   = (const float*)d_in[3];
    const float* Wout = (const float*)d_in[4];
    const float* bout = (const float*)d_in[5];
    const float* W1   = (const float*)d_in[6];
    const float* b1   = (const float*)d_in[7];
    const float* W2   = (const float*)d_in[8];
    const float* b2   = (const float*)d_in[9];
    const float* g2   = (const float*)d_in[10];
    const float* be2  = (const float*)d_in[11];
    const float* gf   = (const float*)d_in[12];
    const float* bf   = (const float*)d_in[13];
    float* out = (float*)d_out;

    // ---- workspace layout ----
    char* w = (char*)d_ws;
    const size_t SZ_X = (size_t)MROWS * DD * 4;               // 33.55 MB
    float*    x     = (float*)(w);
    ushort_t* xhl   = (ushort_t*)(w + SZ_X);
    float*    qkb   = (float*)(w + 2 * SZ_X);
    ushort_t* attb  = (ushort_t*)(w + 2 * SZ_X);
    float*    vb    = (float*)(w + 3 * SZ_X);
    float*    obuf  = (float*)(w + 4 * SZ_X);                 // obuf strip / h1 strip
    ushort_t* h1b   = (ushort_t*)(w + 4 * SZ_X);
    ushort_t* wb    = (ushort_t*)(w + 6 * SZ_X);
    char*     tail  = w + 6 * SZ_X + 5242880 * 2;
    int*      bkt   = (int*)(tail);
    int*      st    = (int*)(tail + (size_t)BHH * NH * TT * 4);
    float*    lseb  = (float*)(tail + 2 * (size_t)BHH * NH * TT * 4);

    const size_t XHALF = (size_t)MROWS * DD;
    ushort_t* xh = xhl;            ushort_t* xl = xhl + XHALF;
    ushort_t* wvh = wb;            ushort_t* wvl = wb + 262144;
    ushort_t* woh = wb + 524288;   ushort_t* wol = wb + 786432;
    ushort_t* w1h = wb + 1048576;  ushort_t* w1l = wb + 2097152;
    ushort_t* w2h = wb + 3145728;  ushort_t* w2l = wb + 4194304;
    const size_t H1HALF = (size_t)8192 * DFFN;
    ushort_t* h1h = h1b;           ushort_t* h1l = h1b + H1HALF;

    hipMemcpyAsync(x, src, SZ_X, hipMemcpyDeviceToDevice, stream);
    cvt_k<<<(MROWS * DD / 4 + 255) / 256, 256, 0, stream>>>(src, xh, xl, MROWS * DD / 4);

    for (int i = 0; i < LLAY; i++) {
        const float* Wqk_i = Wqk + (size_t)i * DD * DD;
        const float* Wv_i  = Wv  + (size_t)i * DD * DD;
        const float* Wout_i= Wout+ (size_t)i * DD * DD;
        const float* bout_i= bout+ (size_t)i * DD;
        const float* W1_i  = W1  + (size_t)i * DFFN * DD;
        const float* b1_i  = b1  + (size_t)i * DFFN;
        const float* W2_i  = W2  + (size_t)i * DD * DFFN;
        const float* b2_i  = b2  + (size_t)i * DD;
        const float* g2_i  = g2  + (size_t)i * DD;
        const float* be2_i = be2 + (size_t)i * DD;
        const float* rot_i = rots + (size_t)i * DHH * NH * 32;

        cvt_k<<<(262144 / 4 + 255) / 256, 256, 0, stream>>>(Wv_i, wvh, wvl, 262144 / 4);
        cvt_k<<<(262144 / 4 + 255) / 256, 256, 0, stream>>>(Wout_i, woh, wol, 262144 / 4);
        cvt_k<<<(1048576 / 4 + 255) / 256, 256, 0, stream>>>(W1_i, w1h, w1l, 1048576 / 4);
        cvt_k<<<(1048576 / 4 + 255) / 256, 256, 0, stream>>>(W2_i, w2h, w2l, 1048576 / 4);

        // qk = x @ Wqk^T  (fp32: feeds LSH argmax)
        gemm_k<<<dim3(4, 128), 256, 0, stream>>>(x, Wqk_i, nullptr, nullptr, qkb,
                                                 MROWS, DD, DD, 0);
        // v = x @ Wv^T  (bf16x3)
        gemm_bf3_k<<<dim3(4, 128), 256, 0, stream>>>(xh, xl, DD, wvh, wvl,
                                                     nullptr, nullptr, vb, nullptr, nullptr,
                                                     MROWS, DD, DD, 0);
        bucket_k<<<dim3(16, NH, BHH), 256, 0, stream>>>(qkb, rot_i, bkt);
        sort_k<<<dim3(NH, BHH), 256, 0, stream>>>(bkt, st);

        for (int s = 0; s < 2; s++) {
            attn_k<<<dim3(NC, 16), 256, 0, stream>>>(qkb, vb, st, obuf, lseb, s * 16);
            combine_k<<<16384, 256, 0, stream>>>(obuf, lseb, attb, s * 16);
        }

        // x = x + att @ Wout^T + bout ; emit x hi/lo
        gemm_bf3_k<<<dim3(4, 128), 256, 0, stream>>>(attb, attb + 512, 1024, woh, wol,
                                                     bout_i, x, x, xh, xl,
                                                     MROWS, DD, DD, 0);
        for (int s = 0; s < 2; s++) {
            const size_t ro = (size_t)s * 8192;
            gemm_bf3_k<<<dim3(16, 64), 256, 0, stream>>>(xh + ro * DD, xl + ro * DD, DD,
                                                         w1h, w1l, b1_i, nullptr,
                                                         nullptr, h1h, h1l,
                                                         8192, DFFN, DD, 1);
            gemm_bf3_k<<<dim3(4, 64), 256, 0, stream>>>(h1h, h1l, DFFN, w2h, w2l,
                                                        b2_i, x + ro * DD,
                                                        vb + ro * DD, nullptr, nullptr,
                                                        8192, DD, DFFN, 0);
        }
        ln_k<<<MROWS, 64, 0, stream>>>(vb, g2_i, be2_i, x, xh, xl);
    }
    ln_k<<<MROWS, 64, 0, stream>>>(x, gf, bf, out, nullptr, nullptr);
}